// Round 6
// baseline (1069.540 us; speedup 1.0000x reference)
//
#include <hip/hip_runtime.h>

#define NN   100000
#define EE   1600000
#define GG   64
#define HIDC 128
#define LL   4
#define NBK  391          // ceil(NN/256) buckets of 256 nodes
#define BCAP 64           // LDS bin capacity per bucket in k_binA

typedef unsigned short u16;
typedef unsigned int   u32;
typedef __attribute__((ext_vector_type(8))) short short8v;
typedef __attribute__((ext_vector_type(4))) float f32x4;

__device__ __forceinline__ u16 f2bf(float f){
    u32 u = __float_as_uint(f);
    u32 r = (u + 0x7fffu + ((u >> 16) & 1u)) >> 16;
    return (u16)r;
}
__device__ __forceinline__ float bfl(u32 u){ return __uint_as_float(u << 16); }
__device__ __forceinline__ float bfh(u32 u){ return __uint_as_float(u & 0xffff0000u); }
__device__ __forceinline__ float bf1(u16 u){ return __uint_as_float(((u32)u) << 16); }

// ---------------- weight packing: fp32 [K=128][M] -> bf16 MFMA B-frag order ----
__global__ __launch_bounds__(256) void k_pack(const float* lin_w, const float* bases_w,
                                              const float* comb_w, u16* wpack){
    int t = blockIdx.x * 256 + threadIdx.x;
    if (t >= 98304) return;
    int li, m, isLin;
    if (t < 16384){ isLin = 1; li = 0; m = t; }
    else { isLin = 0; int u = t - 16384; li = u / 20480; m = u % 20480; }
    int j = m & 7, lane = (m >> 3) & 63, kt = (m >> 9) & 3, ct = m >> 11;
    int k = kt * 32 + ((lane >> 4) << 3) + j;
    int c = ct * 16 + (lane & 15);
    float v;
    if (isLin) v = lin_w[k * HIDC + c];
    else       v = (c < 64) ? bases_w[(li * HIDC + k) * 64 + c]
                            : comb_w[(li * HIDC + k) * 96 + (c - 64)];
    wpack[t] = f2bf(v);
}

// ---------------- CSR build ----------------
__global__ __launch_bounds__(256) void k_hist(const int* dst, int* deg){
    int e = blockIdx.x * 256 + threadIdx.x;
    if (e < EE) atomicAdd(&deg[dst[e]], 1);
}

__global__ __launch_bounds__(256) void k_scan1(const int* deg, int* bsums){
    __shared__ int sd[256];
    int b = blockIdx.x, t = threadIdx.x, base = b * 1024;
    int s = 0;
    for (int j = 0; j < 4; ++j){ int i = base + j * 256 + t; if (i < NN) s += deg[i]; }
    sd[t] = s; __syncthreads();
    for (int o = 128; o > 0; o >>= 1){ if (t < o) sd[t] += sd[t + o]; __syncthreads(); }
    if (t == 0) bsums[b] = sd[0];
}

__global__ void k_scan2(const int* bsums, int* boffs, int nb){
    if (threadIdx.x == 0 && blockIdx.x == 0){
        int run = 0;
        for (int b = 0; b < nb; ++b){ boffs[b] = run; run += bsums[b]; }
    }
}

__global__ __launch_bounds__(256) void k_scan3(const int* deg, const int* boffs, int* rowptr){
    __shared__ int ss[256];
    int b = blockIdx.x, t = threadIdx.x, base = b * 1024;
    int v[4]; int s = 0;
    for (int j = 0; j < 4; ++j){ int i = base + t * 4 + j; v[j] = (i < NN) ? deg[i] : 0; s += v[j]; }
    ss[t] = s; __syncthreads();
    for (int o = 1; o < 256; o <<= 1){
        int val = 0; if (t >= o) val = ss[t - o];
        __syncthreads(); ss[t] += val; __syncthreads();
    }
    int run = boffs[b] + (ss[t] - s);
    for (int j = 0; j < 4; ++j){ int i = base + t * 4 + j; if (i < NN) rowptr[i] = run; run += v[j]; }
    if (b == 0 && t == 0) rowptr[NN] = EE;
}

__global__ void k_ginit(const int* rowptr, int* gcur){
    int b = blockIdx.x * 256 + threadIdx.x;
    if (b < NBK) gcur[b] = rowptr[min(b << 8, NN)];
}

// --------- phase A: bin edges into 256-node buckets (coalesced bucket runs) ----
#define CHUNKA 16384
__global__ __launch_bounds__(256) void k_binA(const int* __restrict__ src,
                                              const int* __restrict__ dst,
                                              int* gcur, u32* esort){
    __shared__ int cnt[NBK];
    __shared__ u32 bins[NBK * BCAP];
    int tid = threadIdx.x;
    for (int i = tid; i < NBK; i += 256) cnt[i] = 0;
    __syncthreads();
    size_t base = (size_t)blockIdx.x * CHUNKA;
    for (int it = 0; it < CHUNKA / 256; ++it){
        size_t e = base + it * 256 + tid;
        if (e < EE){
            int s = src[e], d = dst[e];
            int b = d >> 8;
            u32 p = ((u32)(d & 255) << 17) | (u32)s;
            int pos = atomicAdd(&cnt[b], 1);
            if (pos < BCAP) bins[b * BCAP + pos] = p;
            else { int g = atomicAdd(&gcur[b], 1); esort[g] = p; }   // rare overflow
        }
    }
    __syncthreads();
    int wv = tid >> 6, lane = tid & 63;
    for (int b = wv; b < NBK; b += 4){
        int c = min(cnt[b], BCAP);
        int gb;
        if (lane == 0) gb = atomicAdd(&gcur[b], c);
        gb = __shfl(gb, 0);
        for (int k = lane; k < c; k += 64) esort[gb + k] = bins[b * BCAP + k];
    }
}

// --------- phase B: fine scatter within one bucket (L2-local 16KB window) ------
__global__ __launch_bounds__(256) void k_binB(const u32* __restrict__ esort,
                                              const int* __restrict__ rowptr,
                                              int* fill, int* ssrc){
    int b = blockIdx.x;
    int n0 = b << 8;
    int gs = rowptr[n0];
    int ge = rowptr[min(n0 + 256, NN)];
    for (int i = gs + threadIdx.x; i < ge; i += 256){
        u32 p = esort[i];
        int d = n0 + (int)(p >> 17);
        int s = (int)(p & 0x1FFFFu);
        int pos = rowptr[d] + atomicAdd(&fill[d], 1);
        ssrc[pos] = s;
    }
}

// ------------- fused: lin GEMM (x @ lin_w + b) -> hout fp32 + layer-0 GEMM -----
__global__ __launch_bounds__(256) void k_lin_gemm0(const float* x, const u16* wpack,
                                                   const float* lin_b, const float* comb_b0,
                                                   float* hout, u16* basesb, u16* wcoefb){
    __shared__ u16 lA[16 * 136];
    int tid = threadIdx.x;
    int lane = tid & 63, wv = tid >> 6;
    int n0 = blockIdx.x * 16;
    int l15 = lane & 15, lhi = lane >> 4;

    const float* xr = x + (size_t)(n0 + l15) * HIDC;
    short8v a[4];
    for (int kt = 0; kt < 4; ++kt){
        const float4* p = (const float4*)(xr + kt * 32 + lhi * 8);
        float4 f0 = p[0], f1 = p[1];
        short8v tv;
        tv[0]=(short)f2bf(f0.x); tv[1]=(short)f2bf(f0.y); tv[2]=(short)f2bf(f0.z); tv[3]=(short)f2bf(f0.w);
        tv[4]=(short)f2bf(f1.x); tv[5]=(short)f2bf(f1.y); tv[6]=(short)f2bf(f1.z); tv[7]=(short)f2bf(f1.w);
        a[kt] = tv;
    }
    for (int ct = wv; ct < 8; ct += 4){
        const short8v* bp = ((const short8v*)wpack) + ct * 256 + lane;
        f32x4 acc = {0.f, 0.f, 0.f, 0.f};
        acc = __builtin_amdgcn_mfma_f32_16x16x32_bf16(a[0], bp[0],   acc, 0, 0, 0);
        acc = __builtin_amdgcn_mfma_f32_16x16x32_bf16(a[1], bp[64],  acc, 0, 0, 0);
        acc = __builtin_amdgcn_mfma_f32_16x16x32_bf16(a[2], bp[128], acc, 0, 0, 0);
        acc = __builtin_amdgcn_mfma_f32_16x16x32_bf16(a[3], bp[192], acc, 0, 0, 0);
        int rl0 = lhi * 4, col = ct * 16 + l15;
        float bb = lin_b[col];
        for (int r = 0; r < 4; ++r){
            float v = acc[r] + bb;
            hout[(size_t)(n0 + rl0 + r) * HIDC + col] = v;
            lA[(rl0 + r) * 136 + col] = f2bf(v);
        }
    }
    __syncthreads();

    const u16* ar = lA + l15 * 136;
    short8v b0 = *(const short8v*)(ar + lhi * 8);
    short8v b1 = *(const short8v*)(ar + 32 + lhi * 8);
    short8v b2 = *(const short8v*)(ar + 64 + lhi * 8);
    short8v b3 = *(const short8v*)(ar + 96 + lhi * 8);
    const u16* wl = wpack + 16384;
    for (int ct = wv; ct < 10; ct += 4){
        const short8v* bp = ((const short8v*)wl) + ct * 256 + lane;
        f32x4 acc = {0.f, 0.f, 0.f, 0.f};
        acc = __builtin_amdgcn_mfma_f32_16x16x32_bf16(b0, bp[0],   acc, 0, 0, 0);
        acc = __builtin_amdgcn_mfma_f32_16x16x32_bf16(b1, bp[64],  acc, 0, 0, 0);
        acc = __builtin_amdgcn_mfma_f32_16x16x32_bf16(b2, bp[128], acc, 0, 0, 0);
        acc = __builtin_amdgcn_mfma_f32_16x16x32_bf16(b3, bp[192], acc, 0, 0, 0);
        int r0 = n0 + lhi * 4, col = ct * 16 + l15;
        if (ct < 4){
            for (int r = 0; r < 4; ++r)
                basesb[(size_t)(r0 + r) * 64 + col] = f2bf(acc[r]);
        } else {
            int c = col - 64;
            float bb = comb_b0[c];
            for (int r = 0; r < 4; ++r)
                wcoefb[(size_t)(r0 + r) * 96 + c] = f2bf(acc[r] + bb);
        }
    }
}

// ------------- fused: edge aggregation (1 node/wave, deep MLP) + combine -------
__global__ __launch_bounds__(256) void k_aggcmb(const u16* __restrict__ basesb,
                                                const int* __restrict__ rowptr,
                                                const int* __restrict__ ssrc,
                                                const u16* __restrict__ wcoefb,
                                                const float* __restrict__ conv_b_l,
                                                u16* __restrict__ gbufb){
    __shared__ float sAgg[4 * 128];
    __shared__ float sInv[4];
    int tid = threadIdx.x;
    int wv = tid >> 6, lane = tid & 63;
    int half = lane >> 5, sl = lane & 31, l15 = lane & 15;
    int n = blockIdx.x * 4 + wv;
    int rp0 = rowptr[n], rp1 = rowptr[n + 1];
    float s0 = 0.f, s1 = 0.f, m0 = -INFINITY, m1 = -INFINITY;

    int e0 = rp0;
    // main loop: 16-edge chunks; indices in registers via shuffle broadcast,
    // 8 independent gathers in flight per half-wave
    for (; e0 + 16 <= rp1; e0 += 16){
        int idxv = ssrc[e0 + l15];
        #pragma unroll
        for (int j = 0; j < 8; ++j){
            int i = __shfl(idxv, 2 * j + half);
            u32 u = *(const u32*)(basesb + ((size_t)i << 6) + 2 * sl);
            float f0 = bfl(u), f1 = bfh(u);
            s0 += f0; s1 += f1;
            m0 = fmaxf(m0, f0); m1 = fmaxf(m1, f1);
        }
    }
    // tail: up to 15 edges, clamped index vector + predicated gathers
    {
        int r = rp1 - e0;
        if (r > 0){
            int idxc = ssrc[min(e0 + l15, rp1 - 1)];
            #pragma unroll
            for (int j = 0; j < 8; ++j){
                int i = __shfl(idxc, 2 * j + half);
                if (2 * j + half < r){
                    u32 u = *(const u32*)(basesb + ((size_t)i << 6) + 2 * sl);
                    float f0 = bfl(u), f1 = bfh(u);
                    s0 += f0; s1 += f1;
                    m0 = fmaxf(m0, f0); m1 = fmaxf(m1, f1);
                }
            }
        }
    }
    // merge the two half-waves
    s0 += __shfl_xor(s0, 32); s1 += __shfl_xor(s1, 32);
    m0 = fmaxf(m0, __shfl_xor(m0, 32));
    m1 = fmaxf(m1, __shfl_xor(m1, 32));
    int degn = rp1 - rp0;
    if (degn == 0){ m0 = 0.f; m1 = 0.f; }
    if (half == 0){
        float* ap = sAgg + wv * 128;
        *(float2*)(ap + 2 * sl)      = make_float2(s0, s1);
        *(float2*)(ap + 64 + 2 * sl) = make_float2(m0, m1);
        if (sl == 0) sInv[wv] = 1.0f / fmaxf((float)degn, 1.0f);
    }
    __syncthreads();

    // phase 2: g = einsum(w, [sum; mean; max]) + conv_b  -> gbuf (bf16)
    int c = tid & 127, sub = tid >> 7;
    int f = c & 15, hh = c >> 4;
    float cb = conv_b_l[c];
    for (int i = 0; i < 2; ++i){
        int nb = i * 2 + sub;
        int n2 = blockIdx.x * 4 + nb;
        const u32* wu = (const u32*)(wcoefb + (size_t)n2 * 96 + hh * 12);
        u32 q0 = wu[0], q1 = wu[1], q2 = wu[2], q3 = wu[3], q4 = wu[4], q5 = wu[5];
        const float* ap = sAgg + nb * 128;
        float inv = sInv[nb];
        float sA = ap[f],      sB = ap[16 + f], sC = ap[32 + f], sD = ap[48 + f];
        float xA = ap[64 + f], xB = ap[80 + f], xC = ap[96 + f], xD = ap[112 + f];
        float g = cb;
        g += bfl(q0) * sA + bfh(q0) * sB + bfl(q1) * sC + bfh(q1) * sD;
        g += (bfl(q2) * sA + bfh(q2) * sB + bfl(q3) * sC + bfh(q3) * sD) * inv;
        g += bfl(q4) * xA + bfh(q4) * xB + bfl(q5) * xC + bfh(q5) * xD;
        gbufb[(size_t)n2 * HIDC + c] = f2bf(g);
    }
}

// ------------- per-graph stats from gbuf (bf16): few atomics ------------------
__global__ __launch_bounds__(256) void k_stats(const u16* __restrict__ gbufb,
                                               const int* __restrict__ batch,
                                               float* gs1, float* gs2){
    int tid = threadIdx.x;
    int c = tid & 127, sub = tid >> 7;
    int n0 = blockIdx.x * 500;
    float accS = 0.f, accS2 = 0.f; int curG = -1;
    for (int i = 0; i < 250; ++i){
        int n = n0 + i * 2 + sub;
        float g = bf1(gbufb[(size_t)n * HIDC + c]);
        int bg = batch[n];
        if (bg != curG){
            if (curG >= 0){
                atomicAdd(&gs1[curG * HIDC + c], accS);
                atomicAdd(&gs2[curG * HIDC + c], accS2);
            }
            curG = bg; accS = 0.f; accS2 = 0.f;
        }
        accS += g; accS2 += g * g;
    }
    if (curG >= 0){
        atomicAdd(&gs1[curG * HIDC + c], accS);
        atomicAdd(&gs2[curG * HIDC + c], accS2);
    }
}

__global__ __launch_bounds__(256) void k_finalize(float* gs1, float* gs2, const int* npg,
                                                  const float* gn_ms_l, const float* gn_w_l,
                                                  float* meanms, float* winv){
    int idx = blockIdx.x * 256 + threadIdx.x;   // 8192
    int bg = idx >> 7, c = idx & 127;
    float cnt = fmaxf((float)npg[bg], 1.0f);
    float s1 = gs1[idx], s2 = gs2[idx];
    float mean = s1 / cnt, ex2 = s2 / cnt;
    float ms = gn_ms_l[c];
    float var = ex2 - mean * mean * ms * (2.0f - ms);
    float inv = rsqrtf(fmaxf(var, 0.f) + 1e-6f);
    meanms[idx] = mean * ms;
    winv[idx]   = gn_w_l[c] * inv;
    gs1[idx] = 0.f; gs2[idx] = 0.f;   // reset for next layer
}

// ------------- fused: norm+relu+residual -> h, then next-layer GEMM ------------
__global__ __launch_bounds__(256) void k_upgemm(const u16* __restrict__ gbufb,
                                                const int* __restrict__ batch,
                                                const float* meanms, const float* winv,
                                                const float* gn_b_l, float* hout,
                                                const u16* wp_next, const float* comb_b_next,
                                                u16* basesb, u16* wcoefb){
    __shared__ u16 lA[16 * 136];
    int tid = threadIdx.x;
    int n0 = blockIdx.x * 16;
    {
        int c = tid & 127, half = tid >> 7;
        float gb = gn_b_l[c];
        for (int i = 0; i < 8; ++i){
            int r = i * 2 + half;
            int n = n0 + r;
            int bg = batch[n];
            float g = bf1(gbufb[(size_t)n * HIDC + c]);
            float val = fmaxf((g - meanms[bg * HIDC + c]) * winv[bg * HIDC + c] + gb, 0.f);
            float hn = hout[(size_t)n * HIDC + c] + val;
            hout[(size_t)n * HIDC + c] = hn;
            lA[r * 136 + c] = f2bf(hn);
        }
    }
    __syncthreads();

    int lane = tid & 63, wv = tid >> 6;
    int l15 = lane & 15, lhi = lane >> 4;
    const u16* ar = lA + l15 * 136;
    short8v b0 = *(const short8v*)(ar + lhi * 8);
    short8v b1 = *(const short8v*)(ar + 32 + lhi * 8);
    short8v b2 = *(const short8v*)(ar + 64 + lhi * 8);
    short8v b3 = *(const short8v*)(ar + 96 + lhi * 8);
    for (int ct = wv; ct < 10; ct += 4){
        const short8v* bp = ((const short8v*)wp_next) + ct * 256 + lane;
        f32x4 acc = {0.f, 0.f, 0.f, 0.f};
        acc = __builtin_amdgcn_mfma_f32_16x16x32_bf16(b0, bp[0],   acc, 0, 0, 0);
        acc = __builtin_amdgcn_mfma_f32_16x16x32_bf16(b1, bp[64],  acc, 0, 0, 0);
        acc = __builtin_amdgcn_mfma_f32_16x16x32_bf16(b2, bp[128], acc, 0, 0, 0);
        acc = __builtin_amdgcn_mfma_f32_16x16x32_bf16(b3, bp[192], acc, 0, 0, 0);
        int r0 = n0 + lhi * 4, col = ct * 16 + l15;
        if (ct < 4){
            for (int r = 0; r < 4; ++r)
                basesb[(size_t)(r0 + r) * 64 + col] = f2bf(acc[r]);
        } else {
            int c = col - 64;
            float bb = comb_b_next[c];
            for (int r = 0; r < 4; ++r)
                wcoefb[(size_t)(r0 + r) * 96 + c] = f2bf(acc[r] + bb);
        }
    }
}

// ------------- last layer: norm+relu+residual + mean-pool accumulation ---------
__global__ __launch_bounds__(256) void k_uplast(const u16* __restrict__ gbufb,
                                                const int* __restrict__ batch,
                                                const float* meanms, const float* winv,
                                                const float* gn_b_l, float* hout, float* ysum){
    int tid = threadIdx.x;
    int c = tid & 127, half = tid >> 7;
    int n0 = blockIdx.x * 8;
    float gb = gn_b_l[c];
    float accY = 0.f; int curG = -1;
    for (int i = 0; i < 4; ++i){
        int n = n0 + i * 2 + half;
        int bg = batch[n];
        float g = bf1(gbufb[(size_t)n * HIDC + c]);
        float val = fmaxf((g - meanms[bg * HIDC + c]) * winv[bg * HIDC + c] + gb, 0.f);
        float hn = hout[(size_t)n * HIDC + c] + val;
        hout[(size_t)n * HIDC + c] = hn;
        if (bg != curG){
            if (curG >= 0) atomicAdd(&ysum[curG * HIDC + c], accY);
            curG = bg; accY = 0.f;
        }
        accY += hn;
    }
    if (curG >= 0) atomicAdd(&ysum[curG * HIDC + c], accY);
}

__global__ __launch_bounds__(256) void k_yscale(float* y, const int* npg){
    int idx = blockIdx.x * 256 + threadIdx.x;  // 8192
    int bg = idx >> 7;
    y[idx] /= fmaxf((float)npg[bg], 1.0f);
}

// ---------------- launch ----------------
extern "C" void kernel_launch(void* const* d_in, const int* in_sizes, int n_in,
                              void* d_out, int out_size, void* d_ws, size_t ws_size,
                              hipStream_t stream){
    const float* x       = (const float*)d_in[0];
    const int*   ei      = (const int*)d_in[1];
    const int*   batch   = (const int*)d_in[2];
    const int*   npg     = (const int*)d_in[3];
    const float* lin_w   = (const float*)d_in[4];
    const float* lin_b   = (const float*)d_in[5];
    const float* bases_w = (const float*)d_in[6];
    const float* comb_w  = (const float*)d_in[7];
    const float* comb_b  = (const float*)d_in[8];
    const float* conv_b  = (const float*)d_in[9];
    const float* gn_w    = (const float*)d_in[10];
    const float* gn_b    = (const float*)d_in[11];
    const float* gn_ms   = (const float*)d_in[12];
    (void)in_sizes; (void)n_in; (void)out_size; (void)ws_size;

    float* hout = (float*)d_out;
    float* yout = hout + (size_t)NN * HIDC;

    char* basep = (char*)d_ws;
    size_t o = 0;
    auto alloc = [&](size_t bytes) -> char* {
        char* p = basep + o;
        o = (o + bytes + 255) & ~(size_t)255;
        return p;
    };
    u16*   wpack  = (u16*)  alloc((size_t)98304 * 2);
    u16*   basesb = (u16*)  alloc((size_t)NN * 64 * 2);
    u16*   wcoefb = (u16*)  alloc((size_t)NN * 96 * 2);
    u16*   gbufb  = (u16*)  alloc((size_t)NN * HIDC * 2);
    int*   deg    = (int*)  alloc((size_t)NN * 4);
    int*   rowptr = (int*)  alloc((size_t)(NN + 1) * 4);
    int*   fill   = (int*)  alloc((size_t)NN * 4);
    int*   ssrc   = (int*)  alloc((size_t)EE * 4);
    u32*   esort  = (u32*)  alloc((size_t)EE * 4);
    int*   gcur   = (int*)  alloc((size_t)NBK * 4);
    int*   bsums  = (int*)  alloc(128 * 4);
    int*   boffs  = (int*)  alloc(128 * 4);
    float* gs1    = (float*)alloc(8192 * 4);
    float* gs2    = (float*)alloc(8192 * 4);
    float* meanms = (float*)alloc(8192 * 4);
    float* winv   = (float*)alloc(8192 * 4);

    hipMemsetAsync(deg,  0, (size_t)NN * 4, stream);
    hipMemsetAsync(fill, 0, (size_t)NN * 4, stream);
    hipMemsetAsync(gs1,  0, (size_t)8192 * 4, stream);
    hipMemsetAsync(gs2,  0, (size_t)8192 * 4, stream);
    hipMemsetAsync(yout, 0, (size_t)8192 * 4, stream);

    k_pack  <<<384,  256, 0, stream>>>(lin_w, bases_w, comb_w, wpack);
    k_hist  <<<6250, 256, 0, stream>>>(ei + EE, deg);
    k_scan1 <<<98,   256, 0, stream>>>(deg, bsums);
    k_scan2 <<<1,    64,  0, stream>>>(bsums, boffs, 98);
    k_scan3 <<<98,   256, 0, stream>>>(deg, boffs, rowptr);
    k_ginit <<<2,    256, 0, stream>>>(rowptr, gcur);
    k_binA  <<<98,   256, 0, stream>>>(ei, ei + EE, gcur, esort);
    k_binB  <<<NBK,  256, 0, stream>>>(esort, rowptr, fill, ssrc);

    k_lin_gemm0<<<6250, 256, 0, stream>>>(x, wpack, lin_b, comb_b, hout, basesb, wcoefb);

    for (int l = 0; l < LL; ++l){
        k_aggcmb  <<<25000, 256, 0, stream>>>(basesb, rowptr, ssrc, wcoefb,
                                              conv_b + l * HIDC, gbufb);
        k_stats   <<<200,   256, 0, stream>>>(gbufb, batch, gs1, gs2);
        k_finalize<<<32,    256, 0, stream>>>(gs1, gs2, npg, gn_ms + l * HIDC,
                                              gn_w + l * HIDC, meanms, winv);
        if (l < 3){
            k_upgemm<<<6250, 256, 0, stream>>>(gbufb, batch, meanms, winv,
                                               gn_b + l * HIDC, hout,
                                               wpack + 16384 + (l + 1) * 20480,
                                               comb_b + (l + 1) * 96, basesb, wcoefb);
        } else {
            k_uplast<<<12500, 256, 0, stream>>>(gbufb, batch, meanms, winv,
                                                gn_b + l * HIDC, hout, yout);
        }
    }
    k_yscale<<<32, 256, 0, stream>>>(yout, npg);
}

// Round 7
// 876.314 us; speedup vs baseline: 1.2205x; 1.2205x over previous
//
#include <hip/hip_runtime.h>

#define NN   100000
#define EE   1600000
#define GG   64
#define HIDC 128
#define LL   4
#define NBK  391          // ceil(NN/256) buckets of 256 nodes
#define BCAP 16           // LDS bin capacity per bucket in k_binA
#define BSTR 17           // bins row stride (bank-conflict-free)
#define SCAP 4608         // binB LDS stage capacity (bucket mean 4096, sd 64)

typedef unsigned short u16;
typedef unsigned int   u32;
typedef __attribute__((ext_vector_type(8))) short short8v;
typedef __attribute__((ext_vector_type(4))) float f32x4;

__device__ __forceinline__ u16 f2bf(float f){
    u32 u = __float_as_uint(f);
    u32 r = (u + 0x7fffu + ((u >> 16) & 1u)) >> 16;
    return (u16)r;
}
__device__ __forceinline__ float bfl(u32 u){ return __uint_as_float(u << 16); }
__device__ __forceinline__ float bfh(u32 u){ return __uint_as_float(u & 0xffff0000u); }
__device__ __forceinline__ float bf1(u16 u){ return __uint_as_float(((u32)u) << 16); }

// ---------------- weight packing: fp32 [K=128][M] -> bf16 MFMA B-frag order ----
__global__ __launch_bounds__(256) void k_pack(const float* lin_w, const float* bases_w,
                                              const float* comb_w, u16* wpack){
    int t = blockIdx.x * 256 + threadIdx.x;
    if (t >= 98304) return;
    int li, m, isLin;
    if (t < 16384){ isLin = 1; li = 0; m = t; }
    else { isLin = 0; int u = t - 16384; li = u / 20480; m = u % 20480; }
    int j = m & 7, lane = (m >> 3) & 63, kt = (m >> 9) & 3, ct = m >> 11;
    int k = kt * 32 + ((lane >> 4) << 3) + j;
    int c = ct * 16 + (lane & 15);
    float v;
    if (isLin) v = lin_w[k * HIDC + c];
    else       v = (c < 64) ? bases_w[(li * HIDC + k) * 64 + c]
                            : comb_w[(li * HIDC + k) * 96 + (c - 64)];
    wpack[t] = f2bf(v);
}

// ---------------- CSR build: bucket histogram -> scan -> bin -> counting sort --
__global__ __launch_bounds__(256) void k_bhist(const int* __restrict__ dst, int* bcnt){
    __shared__ int cnt[NBK];
    int tid = threadIdx.x;
    for (int i = tid; i < NBK; i += 256) cnt[i] = 0;
    __syncthreads();
    size_t base = (size_t)blockIdx.x * 2048;
    for (int it = 0; it < 8; ++it){
        size_t e = base + it * 256 + tid;
        if (e < EE) atomicAdd(&cnt[dst[e] >> 8], 1);
    }
    __syncthreads();
    for (int i = tid; i < NBK; i += 256)
        if (cnt[i]) atomicAdd(&bcnt[i], cnt[i]);
}

__global__ __launch_bounds__(512) void k_bscan(const int* bcnt, int* boff, int* gcur){
    __shared__ int sd[512];
    int tid = threadIdx.x;
    int own = (tid < NBK) ? bcnt[tid] : 0;
    sd[tid] = own; __syncthreads();
    for (int o = 1; o < 512; o <<= 1){
        int v = 0; if (tid >= o) v = sd[tid - o];
        __syncthreads(); sd[tid] += v; __syncthreads();
    }
    if (tid < NBK){
        int ex = sd[tid] - own;
        boff[tid] = ex;
        gcur[tid] = ex;
        if (tid == NBK - 1) boff[NBK] = sd[tid];
    }
}

// bin edges into 256-node buckets; LDS bins with stride 17 (bank-spread)
__global__ __launch_bounds__(256) void k_binA(const int* __restrict__ src,
                                              const int* __restrict__ dst,
                                              int* gcur, u32* esort){
    __shared__ int cnt[NBK];
    __shared__ u32 bins[NBK * BSTR];
    int tid = threadIdx.x;
    for (int i = tid; i < NBK; i += 256) cnt[i] = 0;
    __syncthreads();
    size_t base = (size_t)blockIdx.x * 2048;
    for (int it = 0; it < 8; ++it){
        size_t e = base + it * 256 + tid;
        if (e < EE){
            int s = src[e], d = dst[e];
            int b = d >> 8;
            u32 p = ((u32)(d & 255) << 17) | (u32)s;
            int pos = atomicAdd(&cnt[b], 1);
            if (pos < BCAP) bins[b * BSTR + pos] = p;
            else esort[atomicAdd(&gcur[b], 1)] = p;   // rare overflow
        }
    }
    __syncthreads();
    // per-lane flush: each thread owns <=2 buckets, ~5 entries each
    for (int b = tid; b < NBK; b += 256){
        int c = min(cnt[b], BCAP);
        if (c){
            int g = atomicAdd(&gcur[b], c);
            for (int k = 0; k < c; ++k) esort[g + k] = bins[b * BSTR + k];
        }
    }
}

// per-bucket LDS counting sort: writes rowptr AND node-grouped ssrc (coalesced)
__global__ __launch_bounds__(512) void k_binB(const u32* __restrict__ esort,
                                              const int* __restrict__ boff,
                                              int* rowptr, int* ssrc){
    __shared__ int cnt256[256];
    __shared__ int pref[256];
    __shared__ int fil[256];
    __shared__ int sstage[SCAP];
    int tid = threadIdx.x;
    int b = blockIdx.x;
    int n0 = b << 8;
    int gs = boff[b], ge = boff[b + 1];
    if (tid < 256) cnt256[tid] = 0;
    __syncthreads();
    for (int i = gs + tid; i < ge; i += 512)
        atomicAdd(&cnt256[esort[i] >> 17], 1);
    __syncthreads();
    if (tid < 256) pref[tid] = cnt256[tid];
    __syncthreads();
    for (int o = 1; o < 256; o <<= 1){
        int v = 0; if (tid < 256 && tid >= o) v = pref[tid - o];
        __syncthreads(); if (tid < 256 && tid >= o) pref[tid] += v;
        __syncthreads();
    }
    if (tid < 256){
        int ex = pref[tid] - cnt256[tid];
        fil[tid] = gs + ex;
        int n = n0 + tid;
        if (n < NN) rowptr[n] = gs + ex;
    }
    if (b == NBK - 1 && tid == 0) rowptr[NN] = EE;
    __syncthreads();
    for (int i = gs + tid; i < ge; i += 512){
        u32 p = esort[i];
        int d = (int)(p >> 17);
        int s = (int)(p & 0x1FFFFu);
        int pos = atomicAdd(&fil[d], 1);
        int loc = pos - gs;
        if (loc < SCAP) sstage[loc] = s;
        else ssrc[pos] = s;               // statistical-overflow safety
    }
    __syncthreads();
    int size = ge - gs;
    int lim = min(size, SCAP);
    for (int i = tid; i < lim; i += 512) ssrc[gs + i] = sstage[i];
}

// ------------- fused: lin GEMM (x @ lin_w + b) -> hout fp32 + layer-0 GEMM -----
__global__ __launch_bounds__(256) void k_lin_gemm0(const float* x, const u16* wpack,
                                                   const float* lin_b, const float* comb_b0,
                                                   float* hout, u16* basesb, u16* wcoefb){
    __shared__ u16 lA[16 * 136];
    int tid = threadIdx.x;
    int lane = tid & 63, wv = tid >> 6;
    int n0 = blockIdx.x * 16;
    int l15 = lane & 15, lhi = lane >> 4;

    const float* xr = x + (size_t)(n0 + l15) * HIDC;
    short8v a[4];
    for (int kt = 0; kt < 4; ++kt){
        const float4* p = (const float4*)(xr + kt * 32 + lhi * 8);
        float4 f0 = p[0], f1 = p[1];
        short8v tv;
        tv[0]=(short)f2bf(f0.x); tv[1]=(short)f2bf(f0.y); tv[2]=(short)f2bf(f0.z); tv[3]=(short)f2bf(f0.w);
        tv[4]=(short)f2bf(f1.x); tv[5]=(short)f2bf(f1.y); tv[6]=(short)f2bf(f1.z); tv[7]=(short)f2bf(f1.w);
        a[kt] = tv;
    }
    for (int ct = wv; ct < 8; ct += 4){
        const short8v* bp = ((const short8v*)wpack) + ct * 256 + lane;
        f32x4 acc = {0.f, 0.f, 0.f, 0.f};
        acc = __builtin_amdgcn_mfma_f32_16x16x32_bf16(a[0], bp[0],   acc, 0, 0, 0);
        acc = __builtin_amdgcn_mfma_f32_16x16x32_bf16(a[1], bp[64],  acc, 0, 0, 0);
        acc = __builtin_amdgcn_mfma_f32_16x16x32_bf16(a[2], bp[128], acc, 0, 0, 0);
        acc = __builtin_amdgcn_mfma_f32_16x16x32_bf16(a[3], bp[192], acc, 0, 0, 0);
        int rl0 = lhi * 4, col = ct * 16 + l15;
        float bb = lin_b[col];
        for (int r = 0; r < 4; ++r){
            float v = acc[r] + bb;
            hout[(size_t)(n0 + rl0 + r) * HIDC + col] = v;
            lA[(rl0 + r) * 136 + col] = f2bf(v);
        }
    }
    __syncthreads();

    const u16* ar = lA + l15 * 136;
    short8v b0 = *(const short8v*)(ar + lhi * 8);
    short8v b1 = *(const short8v*)(ar + 32 + lhi * 8);
    short8v b2 = *(const short8v*)(ar + 64 + lhi * 8);
    short8v b3 = *(const short8v*)(ar + 96 + lhi * 8);
    const u16* wl = wpack + 16384;
    for (int ct = wv; ct < 10; ct += 4){
        const short8v* bp = ((const short8v*)wl) + ct * 256 + lane;
        f32x4 acc = {0.f, 0.f, 0.f, 0.f};
        acc = __builtin_amdgcn_mfma_f32_16x16x32_bf16(b0, bp[0],   acc, 0, 0, 0);
        acc = __builtin_amdgcn_mfma_f32_16x16x32_bf16(b1, bp[64],  acc, 0, 0, 0);
        acc = __builtin_amdgcn_mfma_f32_16x16x32_bf16(b2, bp[128], acc, 0, 0, 0);
        acc = __builtin_amdgcn_mfma_f32_16x16x32_bf16(b3, bp[192], acc, 0, 0, 0);
        int r0 = n0 + lhi * 4, col = ct * 16 + l15;
        if (ct < 4){
            for (int r = 0; r < 4; ++r)
                basesb[(size_t)(r0 + r) * 64 + col] = f2bf(acc[r]);
        } else {
            int c = col - 64;
            float bb = comb_b0[c];
            for (int r = 0; r < 4; ++r)
                wcoefb[(size_t)(r0 + r) * 96 + c] = f2bf(acc[r] + bb);
        }
    }
}

// ------------- fused: edge aggregation (1 node/wave, deep MLP) + combine -------
__global__ __launch_bounds__(256) void k_aggcmb(const u16* __restrict__ basesb,
                                                const int* __restrict__ rowptr,
                                                const int* __restrict__ ssrc,
                                                const u16* __restrict__ wcoefb,
                                                const float* __restrict__ conv_b_l,
                                                u16* __restrict__ gbufb){
    __shared__ float sAgg[4 * 128];
    __shared__ float sInv[4];
    int tid = threadIdx.x;
    int wv = tid >> 6, lane = tid & 63;
    int half = lane >> 5, sl = lane & 31, l15 = lane & 15;
    int n = blockIdx.x * 4 + wv;
    int rp0 = rowptr[n], rp1 = rowptr[n + 1];
    float s0 = 0.f, s1 = 0.f, m0 = -INFINITY, m1 = -INFINITY;

    int e0 = rp0;
    for (; e0 + 16 <= rp1; e0 += 16){
        int idxv = ssrc[e0 + l15];
        #pragma unroll
        for (int j = 0; j < 8; ++j){
            int i = __shfl(idxv, 2 * j + half);
            u32 u = *(const u32*)(basesb + ((size_t)i << 6) + 2 * sl);
            float f0 = bfl(u), f1 = bfh(u);
            s0 += f0; s1 += f1;
            m0 = fmaxf(m0, f0); m1 = fmaxf(m1, f1);
        }
    }
    {
        int r = rp1 - e0;
        if (r > 0){
            int idxc = ssrc[min(e0 + l15, rp1 - 1)];
            #pragma unroll
            for (int j = 0; j < 8; ++j){
                int i = __shfl(idxc, 2 * j + half);
                if (2 * j + half < r){
                    u32 u = *(const u32*)(basesb + ((size_t)i << 6) + 2 * sl);
                    float f0 = bfl(u), f1 = bfh(u);
                    s0 += f0; s1 += f1;
                    m0 = fmaxf(m0, f0); m1 = fmaxf(m1, f1);
                }
            }
        }
    }
    s0 += __shfl_xor(s0, 32); s1 += __shfl_xor(s1, 32);
    m0 = fmaxf(m0, __shfl_xor(m0, 32));
    m1 = fmaxf(m1, __shfl_xor(m1, 32));
    int degn = rp1 - rp0;
    if (degn == 0){ m0 = 0.f; m1 = 0.f; }
    if (half == 0){
        float* ap = sAgg + wv * 128;
        *(float2*)(ap + 2 * sl)      = make_float2(s0, s1);
        *(float2*)(ap + 64 + 2 * sl) = make_float2(m0, m1);
        if (sl == 0) sInv[wv] = 1.0f / fmaxf((float)degn, 1.0f);
    }
    __syncthreads();

    int c = tid & 127, sub = tid >> 7;
    int f = c & 15, hh = c >> 4;
    float cb = conv_b_l[c];
    for (int i = 0; i < 2; ++i){
        int nb = i * 2 + sub;
        int n2 = blockIdx.x * 4 + nb;
        const u32* wu = (const u32*)(wcoefb + (size_t)n2 * 96 + hh * 12);
        u32 q0 = wu[0], q1 = wu[1], q2 = wu[2], q3 = wu[3], q4 = wu[4], q5 = wu[5];
        const float* ap = sAgg + nb * 128;
        float inv = sInv[nb];
        float sA = ap[f],      sB = ap[16 + f], sC = ap[32 + f], sD = ap[48 + f];
        float xA = ap[64 + f], xB = ap[80 + f], xC = ap[96 + f], xD = ap[112 + f];
        float g = cb;
        g += bfl(q0) * sA + bfh(q0) * sB + bfl(q1) * sC + bfh(q1) * sD;
        g += (bfl(q2) * sA + bfh(q2) * sB + bfl(q3) * sC + bfh(q3) * sD) * inv;
        g += bfl(q4) * xA + bfh(q4) * xB + bfl(q5) * xC + bfh(q5) * xD;
        gbufb[(size_t)n2 * HIDC + c] = f2bf(g);
    }
}

// ------------- per-graph stats from gbuf (bf16): few atomics ------------------
__global__ __launch_bounds__(256) void k_stats(const u16* __restrict__ gbufb,
                                               const int* __restrict__ batch,
                                               float* gs1, float* gs2){
    int tid = threadIdx.x;
    int c = tid & 127, sub = tid >> 7;
    int n0 = blockIdx.x * 500;
    float accS = 0.f, accS2 = 0.f; int curG = -1;
    for (int i = 0; i < 250; ++i){
        int n = n0 + i * 2 + sub;
        float g = bf1(gbufb[(size_t)n * HIDC + c]);
        int bg = batch[n];
        if (bg != curG){
            if (curG >= 0){
                atomicAdd(&gs1[curG * HIDC + c], accS);
                atomicAdd(&gs2[curG * HIDC + c], accS2);
            }
            curG = bg; accS = 0.f; accS2 = 0.f;
        }
        accS += g; accS2 += g * g;
    }
    if (curG >= 0){
        atomicAdd(&gs1[curG * HIDC + c], accS);
        atomicAdd(&gs2[curG * HIDC + c], accS2);
    }
}

__global__ __launch_bounds__(256) void k_finalize(float* gs1, float* gs2, const int* npg,
                                                  const float* gn_ms_l, const float* gn_w_l,
                                                  float* meanms, float* winv){
    int idx = blockIdx.x * 256 + threadIdx.x;   // 8192
    int bg = idx >> 7, c = idx & 127;
    float cnt = fmaxf((float)npg[bg], 1.0f);
    float s1 = gs1[idx], s2 = gs2[idx];
    float mean = s1 / cnt, ex2 = s2 / cnt;
    float ms = gn_ms_l[c];
    float var = ex2 - mean * mean * ms * (2.0f - ms);
    float inv = rsqrtf(fmaxf(var, 0.f) + 1e-6f);
    meanms[idx] = mean * ms;
    winv[idx]   = gn_w_l[c] * inv;
    gs1[idx] = 0.f; gs2[idx] = 0.f;   // reset for next layer
}

// ------------- fused: norm+relu+residual -> h, then next-layer GEMM ------------
__global__ __launch_bounds__(256) void k_upgemm(const u16* __restrict__ gbufb,
                                                const int* __restrict__ batch,
                                                const float* meanms, const float* winv,
                                                const float* gn_b_l, float* hout,
                                                const u16* wp_next, const float* comb_b_next,
                                                u16* basesb, u16* wcoefb){
    __shared__ u16 lA[16 * 136];
    int tid = threadIdx.x;
    int n0 = blockIdx.x * 16;
    {
        int c = tid & 127, half = tid >> 7;
        float gb = gn_b_l[c];
        for (int i = 0; i < 8; ++i){
            int r = i * 2 + half;
            int n = n0 + r;
            int bg = batch[n];
            float g = bf1(gbufb[(size_t)n * HIDC + c]);
            float val = fmaxf((g - meanms[bg * HIDC + c]) * winv[bg * HIDC + c] + gb, 0.f);
            float hn = hout[(size_t)n * HIDC + c] + val;
            hout[(size_t)n * HIDC + c] = hn;
            lA[r * 136 + c] = f2bf(hn);
        }
    }
    __syncthreads();

    int lane = tid & 63, wv = tid >> 6;
    int l15 = lane & 15, lhi = lane >> 4;
    const u16* ar = lA + l15 * 136;
    short8v b0 = *(const short8v*)(ar + lhi * 8);
    short8v b1 = *(const short8v*)(ar + 32 + lhi * 8);
    short8v b2 = *(const short8v*)(ar + 64 + lhi * 8);
    short8v b3 = *(const short8v*)(ar + 96 + lhi * 8);
    for (int ct = wv; ct < 10; ct += 4){
        const short8v* bp = ((const short8v*)wp_next) + ct * 256 + lane;
        f32x4 acc = {0.f, 0.f, 0.f, 0.f};
        acc = __builtin_amdgcn_mfma_f32_16x16x32_bf16(b0, bp[0],   acc, 0, 0, 0);
        acc = __builtin_amdgcn_mfma_f32_16x16x32_bf16(b1, bp[64],  acc, 0, 0, 0);
        acc = __builtin_amdgcn_mfma_f32_16x16x32_bf16(b2, bp[128], acc, 0, 0, 0);
        acc = __builtin_amdgcn_mfma_f32_16x16x32_bf16(b3, bp[192], acc, 0, 0, 0);
        int r0 = n0 + lhi * 4, col = ct * 16 + l15;
        if (ct < 4){
            for (int r = 0; r < 4; ++r)
                basesb[(size_t)(r0 + r) * 64 + col] = f2bf(acc[r]);
        } else {
            int c = col - 64;
            float bb = comb_b_next[c];
            for (int r = 0; r < 4; ++r)
                wcoefb[(size_t)(r0 + r) * 96 + c] = f2bf(acc[r] + bb);
        }
    }
}

// ------------- last layer: norm+relu+residual + mean-pool accumulation ---------
__global__ __launch_bounds__(256) void k_uplast(const u16* __restrict__ gbufb,
                                                const int* __restrict__ batch,
                                                const float* meanms, const float* winv,
                                                const float* gn_b_l, float* hout, float* ysum){
    int tid = threadIdx.x;
    int c = tid & 127, half = tid >> 7;
    int n0 = blockIdx.x * 8;
    float gb = gn_b_l[c];
    float accY = 0.f; int curG = -1;
    for (int i = 0; i < 4; ++i){
        int n = n0 + i * 2 + half;
        int bg = batch[n];
        float g = bf1(gbufb[(size_t)n * HIDC + c]);
        float val = fmaxf((g - meanms[bg * HIDC + c]) * winv[bg * HIDC + c] + gb, 0.f);
        float hn = hout[(size_t)n * HIDC + c] + val;
        hout[(size_t)n * HIDC + c] = hn;
        if (bg != curG){
            if (curG >= 0) atomicAdd(&ysum[curG * HIDC + c], accY);
            curG = bg; accY = 0.f;
        }
        accY += hn;
    }
    if (curG >= 0) atomicAdd(&ysum[curG * HIDC + c], accY);
}

__global__ __launch_bounds__(256) void k_yscale(float* y, const int* npg){
    int idx = blockIdx.x * 256 + threadIdx.x;  // 8192
    int bg = idx >> 7;
    y[idx] /= fmaxf((float)npg[bg], 1.0f);
}

// ---------------- launch ----------------
extern "C" void kernel_launch(void* const* d_in, const int* in_sizes, int n_in,
                              void* d_out, int out_size, void* d_ws, size_t ws_size,
                              hipStream_t stream){
    const float* x       = (const float*)d_in[0];
    const int*   ei      = (const int*)d_in[1];
    const int*   batch   = (const int*)d_in[2];
    const int*   npg     = (const int*)d_in[3];
    const float* lin_w   = (const float*)d_in[4];
    const float* lin_b   = (const float*)d_in[5];
    const float* bases_w = (const float*)d_in[6];
    const float* comb_w  = (const float*)d_in[7];
    const float* comb_b  = (const float*)d_in[8];
    const float* conv_b  = (const float*)d_in[9];
    const float* gn_w    = (const float*)d_in[10];
    const float* gn_b    = (const float*)d_in[11];
    const float* gn_ms   = (const float*)d_in[12];
    (void)in_sizes; (void)n_in; (void)out_size; (void)ws_size;

    float* hout = (float*)d_out;
    float* yout = hout + (size_t)NN * HIDC;

    char* basep = (char*)d_ws;
    size_t o = 0;
    auto alloc = [&](size_t bytes) -> char* {
        char* p = basep + o;
        o = (o + bytes + 255) & ~(size_t)255;
        return p;
    };
    u16*   wpack  = (u16*)  alloc((size_t)98304 * 2);
    u16*   basesb = (u16*)  alloc((size_t)NN * 64 * 2);
    u16*   wcoefb = (u16*)  alloc((size_t)NN * 96 * 2);
    u16*   gbufb  = (u16*)  alloc((size_t)NN * HIDC * 2);
    int*   rowptr = (int*)  alloc((size_t)(NN + 1) * 4);
    int*   ssrc   = (int*)  alloc((size_t)EE * 4);
    u32*   esort  = (u32*)  alloc((size_t)EE * 4);
    int*   bcnt   = (int*)  alloc((size_t)NBK * 4);
    int*   boff   = (int*)  alloc((size_t)(NBK + 1) * 4);
    int*   gcur   = (int*)  alloc((size_t)NBK * 4);
    float* gs1    = (float*)alloc(8192 * 4);
    float* gs2    = (float*)alloc(8192 * 4);
    float* meanms = (float*)alloc(8192 * 4);
    float* winv   = (float*)alloc(8192 * 4);

    hipMemsetAsync(bcnt, 0, (size_t)NBK * 4, stream);
    hipMemsetAsync(gs1,  0, (size_t)8192 * 4, stream);
    hipMemsetAsync(gs2,  0, (size_t)8192 * 4, stream);
    hipMemsetAsync(yout, 0, (size_t)8192 * 4, stream);

    k_pack <<<384, 256, 0, stream>>>(lin_w, bases_w, comb_w, wpack);
    k_bhist<<<800, 256, 0, stream>>>(ei + EE, bcnt);
    k_bscan<<<1,   512, 0, stream>>>(bcnt, boff, gcur);
    k_binA <<<800, 256, 0, stream>>>(ei, ei + EE, gcur, esort);
    k_binB <<<NBK, 512, 0, stream>>>(esort, boff, rowptr, ssrc);

    k_lin_gemm0<<<6250, 256, 0, stream>>>(x, wpack, lin_b, comb_b, hout, basesb, wcoefb);

    for (int l = 0; l < LL; ++l){
        k_aggcmb  <<<25000, 256, 0, stream>>>(basesb, rowptr, ssrc, wcoefb,
                                              conv_b + l * HIDC, gbufb);
        k_stats   <<<200,   256, 0, stream>>>(gbufb, batch, gs1, gs2);
        k_finalize<<<32,    256, 0, stream>>>(gs1, gs2, npg, gn_ms + l * HIDC,
                                              gn_w + l * HIDC, meanms, winv);
        if (l < 3){
            k_upgemm<<<6250, 256, 0, stream>>>(gbufb, batch, meanms, winv,
                                               gn_b + l * HIDC, hout,
                                               wpack + 16384 + (l + 1) * 20480,
                                               comb_b + (l + 1) * 96, basesb, wcoefb);
        } else {
            k_uplast<<<12500, 256, 0, stream>>>(gbufb, batch, meanms, winv,
                                                gn_b + l * HIDC, hout, yout);
        }
    }
    k_yscale<<<32, 256, 0, stream>>>(yout, npg);
}

// Round 8
// 850.281 us; speedup vs baseline: 1.2579x; 1.0306x over previous
//
#include <hip/hip_runtime.h>

#define NN   100000
#define EE   1600000
#define GG   64
#define HIDC 128
#define LL   4
#define NBK  391          // ceil(NN/256) buckets of 256 nodes
#define BCAP 16           // LDS bin capacity per bucket in k_binA
#define BSTR 17           // bins row stride (bank-conflict-free)
#define SCAP 4608         // binB LDS stage capacity (bucket mean 4096, sd 64)

typedef unsigned short u16;
typedef unsigned int   u32;
typedef __attribute__((ext_vector_type(8))) short short8v;
typedef __attribute__((ext_vector_type(4))) float f32x4;

__device__ __forceinline__ u16 f2bf(float f){
    u32 u = __float_as_uint(f);
    u32 r = (u + 0x7fffu + ((u >> 16) & 1u)) >> 16;
    return (u16)r;
}
__device__ __forceinline__ float bfl(u32 u){ return __uint_as_float(u << 16); }
__device__ __forceinline__ float bfh(u32 u){ return __uint_as_float(u & 0xffff0000u); }
__device__ __forceinline__ float bf1(u16 u){ return __uint_as_float(((u32)u) << 16); }

// ---------------- weight packing: fp32 [K=128][M] -> bf16 MFMA B-frag order ----
__global__ __launch_bounds__(256) void k_pack(const float* lin_w, const float* bases_w,
                                              const float* comb_w, u16* wpack){
    int t = blockIdx.x * 256 + threadIdx.x;
    if (t >= 98304) return;
    int li, m, isLin;
    if (t < 16384){ isLin = 1; li = 0; m = t; }
    else { isLin = 0; int u = t - 16384; li = u / 20480; m = u % 20480; }
    int j = m & 7, lane = (m >> 3) & 63, kt = (m >> 9) & 3, ct = m >> 11;
    int k = kt * 32 + ((lane >> 4) << 3) + j;
    int c = ct * 16 + (lane & 15);
    float v;
    if (isLin) v = lin_w[k * HIDC + c];
    else       v = (c < 64) ? bases_w[(li * HIDC + k) * 64 + c]
                            : comb_w[(li * HIDC + k) * 96 + (c - 64)];
    wpack[t] = f2bf(v);
}

// ---------------- CSR build: bucket histogram -> scan -> bin -> counting sort --
__global__ __launch_bounds__(256) void k_bhist(const int* __restrict__ dst, int* bcnt){
    __shared__ int cnt[NBK];
    int tid = threadIdx.x;
    for (int i = tid; i < NBK; i += 256) cnt[i] = 0;
    __syncthreads();
    size_t base = (size_t)blockIdx.x * 2048;
    for (int it = 0; it < 8; ++it){
        size_t e = base + it * 256 + tid;
        if (e < EE) atomicAdd(&cnt[dst[e] >> 8], 1);
    }
    __syncthreads();
    for (int i = tid; i < NBK; i += 256)
        if (cnt[i]) atomicAdd(&bcnt[i], cnt[i]);
}

__global__ __launch_bounds__(512) void k_bscan(const int* bcnt, int* boff, int* gcur){
    __shared__ int sd[512];
    int tid = threadIdx.x;
    int own = (tid < NBK) ? bcnt[tid] : 0;
    sd[tid] = own; __syncthreads();
    for (int o = 1; o < 512; o <<= 1){
        int v = 0; if (tid >= o) v = sd[tid - o];
        __syncthreads(); sd[tid] += v; __syncthreads();
    }
    if (tid < NBK){
        int ex = sd[tid] - own;
        boff[tid] = ex;
        gcur[tid] = ex;
        if (tid == NBK - 1) boff[NBK] = sd[tid];
    }
}

// bin edges into 256-node buckets; LDS bins with stride 17 (bank-spread)
__global__ __launch_bounds__(256) void k_binA(const int* __restrict__ src,
                                              const int* __restrict__ dst,
                                              int* gcur, u32* esort){
    __shared__ int cnt[NBK];
    __shared__ u32 bins[NBK * BSTR];
    int tid = threadIdx.x;
    for (int i = tid; i < NBK; i += 256) cnt[i] = 0;
    __syncthreads();
    size_t base = (size_t)blockIdx.x * 2048;
    for (int it = 0; it < 8; ++it){
        size_t e = base + it * 256 + tid;
        if (e < EE){
            int s = src[e], d = dst[e];
            int b = d >> 8;
            u32 p = ((u32)(d & 255) << 17) | (u32)s;
            int pos = atomicAdd(&cnt[b], 1);
            if (pos < BCAP) bins[b * BSTR + pos] = p;
            else esort[atomicAdd(&gcur[b], 1)] = p;   // rare overflow
        }
    }
    __syncthreads();
    for (int b = tid; b < NBK; b += 256){
        int c = min(cnt[b], BCAP);
        if (c){
            int g = atomicAdd(&gcur[b], c);
            for (int k = 0; k < c; ++k) esort[g + k] = bins[b * BSTR + k];
        }
    }
}

// per-bucket LDS counting sort: writes rowptr AND node-grouped ssrc (coalesced)
__global__ __launch_bounds__(512) void k_binB(const u32* __restrict__ esort,
                                              const int* __restrict__ boff,
                                              int* rowptr, int* ssrc){
    __shared__ int cnt256[256];
    __shared__ int pref[256];
    __shared__ int fil[256];
    __shared__ int sstage[SCAP];
    int tid = threadIdx.x;
    int b = blockIdx.x;
    int n0 = b << 8;
    int gs = boff[b], ge = boff[b + 1];
    if (tid < 256) cnt256[tid] = 0;
    __syncthreads();
    for (int i = gs + tid; i < ge; i += 512)
        atomicAdd(&cnt256[esort[i] >> 17], 1);
    __syncthreads();
    if (tid < 256) pref[tid] = cnt256[tid];
    __syncthreads();
    for (int o = 1; o < 256; o <<= 1){
        int v = 0; if (tid < 256 && tid >= o) v = pref[tid - o];
        __syncthreads(); if (tid < 256 && tid >= o) pref[tid] += v;
        __syncthreads();
    }
    if (tid < 256){
        int ex = pref[tid] - cnt256[tid];
        fil[tid] = gs + ex;
        int n = n0 + tid;
        if (n < NN) rowptr[n] = gs + ex;
    }
    if (b == NBK - 1 && tid == 0) rowptr[NN] = EE;
    __syncthreads();
    for (int i = gs + tid; i < ge; i += 512){
        u32 p = esort[i];
        int d = (int)(p >> 17);
        int s = (int)(p & 0x1FFFFu);
        int pos = atomicAdd(&fil[d], 1);
        int loc = pos - gs;
        if (loc < SCAP) sstage[loc] = s;
        else ssrc[pos] = s;               // statistical-overflow safety
    }
    __syncthreads();
    int size = ge - gs;
    int lim = min(size, SCAP);
    for (int i = tid; i < lim; i += 512) ssrc[gs + i] = sstage[i];
}

// ------------- fused: lin GEMM -> hbf (bf16) + layer-0 GEMM --------------------
__global__ __launch_bounds__(256) void k_lin_gemm0(const float* x, const u16* wpack,
                                                   const float* lin_b, const float* comb_b0,
                                                   u16* hbf, u16* basesb, u16* wcoefb){
    __shared__ u16 lA[16 * 136];
    int tid = threadIdx.x;
    int lane = tid & 63, wv = tid >> 6;
    int n0 = blockIdx.x * 16;
    int l15 = lane & 15, lhi = lane >> 4;

    const float* xr = x + (size_t)(n0 + l15) * HIDC;
    short8v a[4];
    for (int kt = 0; kt < 4; ++kt){
        const float4* p = (const float4*)(xr + kt * 32 + lhi * 8);
        float4 f0 = p[0], f1 = p[1];
        short8v tv;
        tv[0]=(short)f2bf(f0.x); tv[1]=(short)f2bf(f0.y); tv[2]=(short)f2bf(f0.z); tv[3]=(short)f2bf(f0.w);
        tv[4]=(short)f2bf(f1.x); tv[5]=(short)f2bf(f1.y); tv[6]=(short)f2bf(f1.z); tv[7]=(short)f2bf(f1.w);
        a[kt] = tv;
    }
    for (int ct = wv; ct < 8; ct += 4){
        const short8v* bp = ((const short8v*)wpack) + ct * 256 + lane;
        f32x4 acc = {0.f, 0.f, 0.f, 0.f};
        acc = __builtin_amdgcn_mfma_f32_16x16x32_bf16(a[0], bp[0],   acc, 0, 0, 0);
        acc = __builtin_amdgcn_mfma_f32_16x16x32_bf16(a[1], bp[64],  acc, 0, 0, 0);
        acc = __builtin_amdgcn_mfma_f32_16x16x32_bf16(a[2], bp[128], acc, 0, 0, 0);
        acc = __builtin_amdgcn_mfma_f32_16x16x32_bf16(a[3], bp[192], acc, 0, 0, 0);
        int rl0 = lhi * 4, col = ct * 16 + l15;
        float bb = lin_b[col];
        for (int r = 0; r < 4; ++r){
            u16 hb = f2bf(acc[r] + bb);
            hbf[(size_t)(n0 + rl0 + r) * HIDC + col] = hb;
            lA[(rl0 + r) * 136 + col] = hb;
        }
    }
    __syncthreads();

    const u16* ar = lA + l15 * 136;
    short8v b0 = *(const short8v*)(ar + lhi * 8);
    short8v b1 = *(const short8v*)(ar + 32 + lhi * 8);
    short8v b2 = *(const short8v*)(ar + 64 + lhi * 8);
    short8v b3 = *(const short8v*)(ar + 96 + lhi * 8);
    const u16* wl = wpack + 16384;
    for (int ct = wv; ct < 10; ct += 4){
        const short8v* bp = ((const short8v*)wl) + ct * 256 + lane;
        f32x4 acc = {0.f, 0.f, 0.f, 0.f};
        acc = __builtin_amdgcn_mfma_f32_16x16x32_bf16(b0, bp[0],   acc, 0, 0, 0);
        acc = __builtin_amdgcn_mfma_f32_16x16x32_bf16(b1, bp[64],  acc, 0, 0, 0);
        acc = __builtin_amdgcn_mfma_f32_16x16x32_bf16(b2, bp[128], acc, 0, 0, 0);
        acc = __builtin_amdgcn_mfma_f32_16x16x32_bf16(b3, bp[192], acc, 0, 0, 0);
        int r0 = n0 + lhi * 4, col = ct * 16 + l15;
        if (ct < 4){
            for (int r = 0; r < 4; ++r)
                basesb[(size_t)(r0 + r) * 64 + col] = f2bf(acc[r]);
        } else {
            int c = col - 64;
            float bb = comb_b0[c];
            for (int r = 0; r < 4; ++r)
                wcoefb[(size_t)(r0 + r) * 96 + c] = f2bf(acc[r] + bb);
        }
    }
}

// ------------- fused: edge aggregation (dwordx2, 4 edges/wave-load) + combine --
__global__ __launch_bounds__(256) void k_aggcmb(const u16* __restrict__ basesb,
                                                const int* __restrict__ rowptr,
                                                const int* __restrict__ ssrc,
                                                const u16* __restrict__ wcoefb,
                                                const float* __restrict__ conv_b_l,
                                                u16* __restrict__ gbufb){
    __shared__ float sAgg[4 * 128];
    __shared__ float sInv[4];
    int tid = threadIdx.x;
    int wv = tid >> 6, lane = tid & 63;
    int slot = lane >> 4;          // edge-within-quad
    int q = lane & 15;             // channel quad: channels 4q..4q+3
    int n = blockIdx.x * 4 + wv;
    int rp0 = rowptr[n], rp1 = rowptr[n + 1];
    float s0 = 0.f, s1 = 0.f, s2 = 0.f, s3 = 0.f;
    float m0 = -INFINITY, m1 = -INFINITY, m2 = -INFINITY, m3 = -INFINITY;

    int e0 = rp0;
    // main: 8-edge chunks; each dwordx2 load serves 4 edges (16 lanes/row)
    for (; e0 + 8 <= rp1; e0 += 8){
        int idxv = ssrc[e0 + (lane & 7)];
        #pragma unroll
        for (int j = 0; j < 2; ++j){
            int i = __shfl(idxv, j * 4 + slot);
            uint2 u = *(const uint2*)(basesb + ((size_t)i << 6) + 4 * q);
            float f0 = bfl(u.x), f1 = bfh(u.x), f2 = bfl(u.y), f3 = bfh(u.y);
            s0 += f0; s1 += f1; s2 += f2; s3 += f3;
            m0 = fmaxf(m0, f0); m1 = fmaxf(m1, f1);
            m2 = fmaxf(m2, f2); m3 = fmaxf(m3, f3);
        }
    }
    // tail: up to 7 edges
    {
        int r = rp1 - e0;
        if (r > 0){
            int idxc = ssrc[min(e0 + (lane & 7), rp1 - 1)];
            #pragma unroll
            for (int j = 0; j < 2; ++j){
                int i = __shfl(idxc, j * 4 + slot);
                if (j * 4 + slot < r){
                    uint2 u = *(const uint2*)(basesb + ((size_t)i << 6) + 4 * q);
                    float f0 = bfl(u.x), f1 = bfh(u.x), f2 = bfl(u.y), f3 = bfh(u.y);
                    s0 += f0; s1 += f1; s2 += f2; s3 += f3;
                    m0 = fmaxf(m0, f0); m1 = fmaxf(m1, f1);
                    m2 = fmaxf(m2, f2); m3 = fmaxf(m3, f3);
                }
            }
        }
    }
    // butterfly-merge the 4 edge slots (lanes q, q+16, q+32, q+48)
    s0 += __shfl_xor(s0, 16); s1 += __shfl_xor(s1, 16);
    s2 += __shfl_xor(s2, 16); s3 += __shfl_xor(s3, 16);
    m0 = fmaxf(m0, __shfl_xor(m0, 16)); m1 = fmaxf(m1, __shfl_xor(m1, 16));
    m2 = fmaxf(m2, __shfl_xor(m2, 16)); m3 = fmaxf(m3, __shfl_xor(m3, 16));
    s0 += __shfl_xor(s0, 32); s1 += __shfl_xor(s1, 32);
    s2 += __shfl_xor(s2, 32); s3 += __shfl_xor(s3, 32);
    m0 = fmaxf(m0, __shfl_xor(m0, 32)); m1 = fmaxf(m1, __shfl_xor(m1, 32));
    m2 = fmaxf(m2, __shfl_xor(m2, 32)); m3 = fmaxf(m3, __shfl_xor(m3, 32));
    int degn = rp1 - rp0;
    if (degn == 0){ m0 = 0.f; m1 = 0.f; m2 = 0.f; m3 = 0.f; }
    if (slot == 0){
        float* ap = sAgg + wv * 128;
        *(float4*)(ap + 4 * q)      = make_float4(s0, s1, s2, s3);
        *(float4*)(ap + 64 + 4 * q) = make_float4(m0, m1, m2, m3);
        if (q == 0) sInv[wv] = 1.0f / fmaxf((float)degn, 1.0f);
    }
    __syncthreads();

    // phase 2: g = einsum(w, [sum; mean; max]) + conv_b  -> gbuf (bf16)
    int c = tid & 127, sub = tid >> 7;
    int f = c & 15, hh = c >> 4;
    float cb = conv_b_l[c];
    for (int i = 0; i < 2; ++i){
        int nb = i * 2 + sub;
        int n2 = blockIdx.x * 4 + nb;
        const u32* wu = (const u32*)(wcoefb + (size_t)n2 * 96 + hh * 12);
        u32 q0 = wu[0], q1 = wu[1], q2 = wu[2], q3 = wu[3], q4 = wu[4], q5 = wu[5];
        const float* ap = sAgg + nb * 128;
        float inv = sInv[nb];
        float sA = ap[f],      sB = ap[16 + f], sC = ap[32 + f], sD = ap[48 + f];
        float xA = ap[64 + f], xB = ap[80 + f], xC = ap[96 + f], xD = ap[112 + f];
        float g = cb;
        g += bfl(q0) * sA + bfh(q0) * sB + bfl(q1) * sC + bfh(q1) * sD;
        g += (bfl(q2) * sA + bfh(q2) * sB + bfl(q3) * sC + bfh(q3) * sD) * inv;
        g += bfl(q4) * xA + bfh(q4) * xB + bfl(q5) * xC + bfh(q5) * xD;
        gbufb[(size_t)n2 * HIDC + c] = f2bf(g);
    }
}

// ------------- per-graph stats from gbuf (bf16): few atomics ------------------
__global__ __launch_bounds__(256) void k_stats(const u16* __restrict__ gbufb,
                                               const int* __restrict__ batch,
                                               float* gs1, float* gs2){
    int tid = threadIdx.x;
    int c = tid & 127, sub = tid >> 7;
    int n0 = blockIdx.x * 500;
    float accS = 0.f, accS2 = 0.f; int curG = -1;
    for (int i = 0; i < 250; ++i){
        int n = n0 + i * 2 + sub;
        float g = bf1(gbufb[(size_t)n * HIDC + c]);
        int bg = batch[n];
        if (bg != curG){
            if (curG >= 0){
                atomicAdd(&gs1[curG * HIDC + c], accS);
                atomicAdd(&gs2[curG * HIDC + c], accS2);
            }
            curG = bg; accS = 0.f; accS2 = 0.f;
        }
        accS += g; accS2 += g * g;
    }
    if (curG >= 0){
        atomicAdd(&gs1[curG * HIDC + c], accS);
        atomicAdd(&gs2[curG * HIDC + c], accS2);
    }
}

__global__ __launch_bounds__(256) void k_finalize(float* gs1, float* gs2, const int* npg,
                                                  const float* gn_ms_l, const float* gn_w_l,
                                                  float* meanms, float* winv){
    int idx = blockIdx.x * 256 + threadIdx.x;   // 8192
    int bg = idx >> 7, c = idx & 127;
    float cnt = fmaxf((float)npg[bg], 1.0f);
    float s1 = gs1[idx], s2 = gs2[idx];
    float mean = s1 / cnt, ex2 = s2 / cnt;
    float ms = gn_ms_l[c];
    float var = ex2 - mean * mean * ms * (2.0f - ms);
    float inv = rsqrtf(fmaxf(var, 0.f) + 1e-6f);
    meanms[idx] = mean * ms;
    winv[idx]   = gn_w_l[c] * inv;
    gs1[idx] = 0.f; gs2[idx] = 0.f;   // reset for next layer
}

// ------------- fused: norm+relu+residual (bf16 h) -> next-layer GEMM -----------
__global__ __launch_bounds__(256) void k_upgemm(const u16* __restrict__ gbufb,
                                                const int* __restrict__ batch,
                                                const float* meanms, const float* winv,
                                                const float* gn_b_l, u16* hbf,
                                                const u16* wp_next, const float* comb_b_next,
                                                u16* basesb, u16* wcoefb){
    __shared__ u16 lA[16 * 136];
    int tid = threadIdx.x;
    int n0 = blockIdx.x * 16;
    {
        int c = tid & 127, half = tid >> 7;
        float gb = gn_b_l[c];
        for (int i = 0; i < 8; ++i){
            int r = i * 2 + half;
            int n = n0 + r;
            int bg = batch[n];
            float g = bf1(gbufb[(size_t)n * HIDC + c]);
            float val = fmaxf((g - meanms[bg * HIDC + c]) * winv[bg * HIDC + c] + gb, 0.f);
            float hn = bf1(hbf[(size_t)n * HIDC + c]) + val;
            u16 hb = f2bf(hn);
            hbf[(size_t)n * HIDC + c] = hb;
            lA[r * 136 + c] = hb;
        }
    }
    __syncthreads();

    int lane = tid & 63, wv = tid >> 6;
    int l15 = lane & 15, lhi = lane >> 4;
    const u16* ar = lA + l15 * 136;
    short8v b0 = *(const short8v*)(ar + lhi * 8);
    short8v b1 = *(const short8v*)(ar + 32 + lhi * 8);
    short8v b2 = *(const short8v*)(ar + 64 + lhi * 8);
    short8v b3 = *(const short8v*)(ar + 96 + lhi * 8);
    for (int ct = wv; ct < 10; ct += 4){
        const short8v* bp = ((const short8v*)wp_next) + ct * 256 + lane;
        f32x4 acc = {0.f, 0.f, 0.f, 0.f};
        acc = __builtin_amdgcn_mfma_f32_16x16x32_bf16(b0, bp[0],   acc, 0, 0, 0);
        acc = __builtin_amdgcn_mfma_f32_16x16x32_bf16(b1, bp[64],  acc, 0, 0, 0);
        acc = __builtin_amdgcn_mfma_f32_16x16x32_bf16(b2, bp[128], acc, 0, 0, 0);
        acc = __builtin_amdgcn_mfma_f32_16x16x32_bf16(b3, bp[192], acc, 0, 0, 0);
        int r0 = n0 + lhi * 4, col = ct * 16 + l15;
        if (ct < 4){
            for (int r = 0; r < 4; ++r)
                basesb[(size_t)(r0 + r) * 64 + col] = f2bf(acc[r]);
        } else {
            int c = col - 64;
            float bb = comb_b_next[c];
            for (int r = 0; r < 4; ++r)
                wcoefb[(size_t)(r0 + r) * 96 + c] = f2bf(acc[r] + bb);
        }
    }
}

// ------------- last layer: norm+relu+residual -> fp32 hout + mean-pool ---------
__global__ __launch_bounds__(256) void k_uplast(const u16* __restrict__ gbufb,
                                                const int* __restrict__ batch,
                                                const float* meanms, const float* winv,
                                                const float* gn_b_l,
                                                const u16* __restrict__ hbf,
                                                float* hout, float* ysum){
    int tid = threadIdx.x;
    int c = tid & 127, half = tid >> 7;
    int n0 = blockIdx.x * 8;
    float gb = gn_b_l[c];
    float accY = 0.f; int curG = -1;
    for (int i = 0; i < 4; ++i){
        int n = n0 + i * 2 + half;
        int bg = batch[n];
        float g = bf1(gbufb[(size_t)n * HIDC + c]);
        float val = fmaxf((g - meanms[bg * HIDC + c]) * winv[bg * HIDC + c] + gb, 0.f);
        float hn = bf1(hbf[(size_t)n * HIDC + c]) + val;
        hout[(size_t)n * HIDC + c] = hn;
        if (bg != curG){
            if (curG >= 0) atomicAdd(&ysum[curG * HIDC + c], accY);
            curG = bg; accY = 0.f;
        }
        accY += hn;
    }
    if (curG >= 0) atomicAdd(&ysum[curG * HIDC + c], accY);
}

__global__ __launch_bounds__(256) void k_yscale(float* y, const int* npg){
    int idx = blockIdx.x * 256 + threadIdx.x;  // 8192
    int bg = idx >> 7;
    y[idx] /= fmaxf((float)npg[bg], 1.0f);
}

// ---------------- launch ----------------
extern "C" void kernel_launch(void* const* d_in, const int* in_sizes, int n_in,
                              void* d_out, int out_size, void* d_ws, size_t ws_size,
                              hipStream_t stream){
    const float* x       = (const float*)d_in[0];
    const int*   ei      = (const int*)d_in[1];
    const int*   batch   = (const int*)d_in[2];
    const int*   npg     = (const int*)d_in[3];
    const float* lin_w   = (const float*)d_in[4];
    const float* lin_b   = (const float*)d_in[5];
    const float* bases_w = (const float*)d_in[6];
    const float* comb_w  = (const float*)d_in[7];
    const float* comb_b  = (const float*)d_in[8];
    const float* conv_b  = (const float*)d_in[9];
    const float* gn_w    = (const float*)d_in[10];
    const float* gn_b    = (const float*)d_in[11];
    const float* gn_ms   = (const float*)d_in[12];
    (void)in_sizes; (void)n_in; (void)out_size; (void)ws_size;

    float* hout = (float*)d_out;
    float* yout = hout + (size_t)NN * HIDC;

    char* basep = (char*)d_ws;
    size_t o = 0;
    auto alloc = [&](size_t bytes) -> char* {
        char* p = basep + o;
        o = (o + bytes + 255) & ~(size_t)255;
        return p;
    };
    u16*   wpack  = (u16*)  alloc((size_t)98304 * 2);
    u16*   hbf    = (u16*)  alloc((size_t)NN * HIDC * 2);
    u16*   basesb = (u16*)  alloc((size_t)NN * 64 * 2);
    u16*   wcoefb = (u16*)  alloc((size_t)NN * 96 * 2);
    u16*   gbufb  = (u16*)  alloc((size_t)NN * HIDC * 2);
    int*   rowptr = (int*)  alloc((size_t)(NN + 1) * 4);
    int*   ssrc   = (int*)  alloc((size_t)EE * 4);
    u32*   esort  = (u32*)  alloc((size_t)EE * 4);
    int*   bcnt   = (int*)  alloc((size_t)NBK * 4);
    int*   boff   = (int*)  alloc((size_t)(NBK + 1) * 4);
    int*   gcur   = (int*)  alloc((size_t)NBK * 4);
    float* gs1    = (float*)alloc(8192 * 4);
    float* gs2    = (float*)alloc(8192 * 4);
    float* meanms = (float*)alloc(8192 * 4);
    float* winv   = (float*)alloc(8192 * 4);

    hipMemsetAsync(bcnt, 0, (size_t)NBK * 4, stream);
    hipMemsetAsync(gs1,  0, (size_t)8192 * 4, stream);
    hipMemsetAsync(gs2,  0, (size_t)8192 * 4, stream);
    hipMemsetAsync(yout, 0, (size_t)8192 * 4, stream);

    k_pack <<<384, 256, 0, stream>>>(lin_w, bases_w, comb_w, wpack);
    k_bhist<<<800, 256, 0, stream>>>(ei + EE, bcnt);
    k_bscan<<<1,   512, 0, stream>>>(bcnt, boff, gcur);
    k_binA <<<800, 256, 0, stream>>>(ei, ei + EE, gcur, esort);
    k_binB <<<NBK, 512, 0, stream>>>(esort, boff, rowptr, ssrc);

    k_lin_gemm0<<<6250, 256, 0, stream>>>(x, wpack, lin_b, comb_b, hbf, basesb, wcoefb);

    for (int l = 0; l < LL; ++l){
        k_aggcmb  <<<25000, 256, 0, stream>>>(basesb, rowptr, ssrc, wcoefb,
                                              conv_b + l * HIDC, gbufb);
        k_stats   <<<200,   256, 0, stream>>>(gbufb, batch, gs1, gs2);
        k_finalize<<<32,    256, 0, stream>>>(gs1, gs2, npg, gn_ms + l * HIDC,
                                              gn_w + l * HIDC, meanms, winv);
        if (l < 3){
            k_upgemm<<<6250, 256, 0, stream>>>(gbufb, batch, meanms, winv,
                                               gn_b + l * HIDC, hbf,
                                               wpack + 16384 + (l + 1) * 20480,
                                               comb_b + (l + 1) * 96, basesb, wcoefb);
        } else {
            k_uplast<<<12500, 256, 0, stream>>>(gbufb, batch, meanms, winv,
                                                gn_b + l * HIDC, hbf, hout, yout);
        }
    }
    k_yscale<<<32, 256, 0, stream>>>(yout, npg);
}

// Round 9
// 682.228 us; speedup vs baseline: 1.5677x; 1.2463x over previous
//
#include <hip/hip_runtime.h>

#define NN   100000
#define EE   1600000
#define GG   64
#define HIDC 128
#define LL   4
#define NBK  391          // ceil(NN/256) buckets of 256 nodes
#define BCAP 16           // LDS bin capacity per bucket in k_binA
#define BSTR 17           // bins row stride (bank-conflict-free)
#define SCAP 4608         // binB LDS stage capacity (bucket mean 4096, sd 64)

typedef unsigned short u16;
typedef unsigned int   u32;
typedef __attribute__((ext_vector_type(8))) short short8v;
typedef __attribute__((ext_vector_type(4))) float f32x4;

__device__ __forceinline__ u16 f2bf(float f){
    u32 u = __float_as_uint(f);
    u32 r = (u + 0x7fffu + ((u >> 16) & 1u)) >> 16;
    return (u16)r;
}
__device__ __forceinline__ float bfl(u32 u){ return __uint_as_float(u << 16); }
__device__ __forceinline__ float bfh(u32 u){ return __uint_as_float(u & 0xffff0000u); }
__device__ __forceinline__ float bf1(u16 u){ return __uint_as_float(((u32)u) << 16); }

// ---------------- weight packing: fp32 [K=128][M] -> bf16 MFMA B-frag order ----
__global__ __launch_bounds__(256) void k_pack(const float* lin_w, const float* bases_w,
                                              const float* comb_w, u16* wpack){
    int t = blockIdx.x * 256 + threadIdx.x;
    if (t >= 98304) return;
    int li, m, isLin;
    if (t < 16384){ isLin = 1; li = 0; m = t; }
    else { isLin = 0; int u = t - 16384; li = u / 20480; m = u % 20480; }
    int j = m & 7, lane = (m >> 3) & 63, kt = (m >> 9) & 3, ct = m >> 11;
    int k = kt * 32 + ((lane >> 4) << 3) + j;
    int c = ct * 16 + (lane & 15);
    float v;
    if (isLin) v = lin_w[k * HIDC + c];
    else       v = (c < 64) ? bases_w[(li * HIDC + k) * 64 + c]
                            : comb_w[(li * HIDC + k) * 96 + (c - 64)];
    wpack[t] = f2bf(v);
}

// ---------------- CSR build: bucket histogram -> scan -> bin -> counting sort --
__global__ __launch_bounds__(256) void k_bhist(const int* __restrict__ dst, int* bcnt){
    __shared__ int cnt[NBK];
    int tid = threadIdx.x;
    for (int i = tid; i < NBK; i += 256) cnt[i] = 0;
    __syncthreads();
    size_t base = (size_t)blockIdx.x * 2048;
    for (int it = 0; it < 8; ++it){
        size_t e = base + it * 256 + tid;
        if (e < EE) atomicAdd(&cnt[dst[e] >> 8], 1);
    }
    __syncthreads();
    for (int i = tid; i < NBK; i += 256)
        if (cnt[i]) atomicAdd(&bcnt[i], cnt[i]);
}

__global__ __launch_bounds__(512) void k_bscan(const int* bcnt, int* boff, int* gcur){
    __shared__ int sd[512];
    int tid = threadIdx.x;
    int own = (tid < NBK) ? bcnt[tid] : 0;
    sd[tid] = own; __syncthreads();
    for (int o = 1; o < 512; o <<= 1){
        int v = 0; if (tid >= o) v = sd[tid - o];
        __syncthreads(); sd[tid] += v; __syncthreads();
    }
    if (tid < NBK){
        int ex = sd[tid] - own;
        boff[tid] = ex;
        gcur[tid] = ex;
        if (tid == NBK - 1) boff[NBK] = sd[tid];
    }
}

// bin edges into 256-node buckets; LDS bins with stride 17 (bank-spread)
__global__ __launch_bounds__(256) void k_binA(const int* __restrict__ src,
                                              const int* __restrict__ dst,
                                              int* gcur, u32* esort){
    __shared__ int cnt[NBK];
    __shared__ u32 bins[NBK * BSTR];
    int tid = threadIdx.x;
    for (int i = tid; i < NBK; i += 256) cnt[i] = 0;
    __syncthreads();
    size_t base = (size_t)blockIdx.x * 2048;
    for (int it = 0; it < 8; ++it){
        size_t e = base + it * 256 + tid;
        if (e < EE){
            int s = src[e], d = dst[e];
            int b = d >> 8;
            u32 p = ((u32)(d & 255) << 17) | (u32)s;
            int pos = atomicAdd(&cnt[b], 1);
            if (pos < BCAP) bins[b * BSTR + pos] = p;
            else esort[atomicAdd(&gcur[b], 1)] = p;   // rare overflow
        }
    }
    __syncthreads();
    for (int b = tid; b < NBK; b += 256){
        int c = min(cnt[b], BCAP);
        if (c){
            int g = atomicAdd(&gcur[b], c);
            for (int k = 0; k < c; ++k) esort[g + k] = bins[b * BSTR + k];
        }
    }
}

// per-bucket LDS counting sort: writes rowptr AND node-grouped ssrc (coalesced)
__global__ __launch_bounds__(512) void k_binB(const u32* __restrict__ esort,
                                              const int* __restrict__ boff,
                                              int* rowptr, int* ssrc){
    __shared__ int cnt256[256];
    __shared__ int pref[256];
    __shared__ int fil[256];
    __shared__ int sstage[SCAP];
    int tid = threadIdx.x;
    int b = blockIdx.x;
    int n0 = b << 8;
    int gs = boff[b], ge = boff[b + 1];
    if (tid < 256) cnt256[tid] = 0;
    __syncthreads();
    for (int i = gs + tid; i < ge; i += 512)
        atomicAdd(&cnt256[esort[i] >> 17], 1);
    __syncthreads();
    if (tid < 256) pref[tid] = cnt256[tid];
    __syncthreads();
    for (int o = 1; o < 256; o <<= 1){
        int v = 0; if (tid < 256 && tid >= o) v = pref[tid - o];
        __syncthreads(); if (tid < 256 && tid >= o) pref[tid] += v;
        __syncthreads();
    }
    if (tid < 256){
        int ex = pref[tid] - cnt256[tid];
        fil[tid] = gs + ex;
        int n = n0 + tid;
        if (n < NN) rowptr[n] = gs + ex;
    }
    if (b == NBK - 1 && tid == 0) rowptr[NN] = EE;
    __syncthreads();
    for (int i = gs + tid; i < ge; i += 512){
        u32 p = esort[i];
        int d = (int)(p >> 17);
        int s = (int)(p & 0x1FFFFu);
        int pos = atomicAdd(&fil[d], 1);
        int loc = pos - gs;
        if (loc < SCAP) sstage[loc] = s;
        else ssrc[pos] = s;               // statistical-overflow safety
    }
    __syncthreads();
    int size = ge - gs;
    int lim = min(size, SCAP);
    for (int i = tid; i < lim; i += 512) ssrc[gs + i] = sstage[i];
}

// ------------- fused: lin GEMM -> hbf (bf16) + layer-0 GEMM --------------------
__global__ __launch_bounds__(256) void k_lin_gemm0(const float* x, const u16* wpack,
                                                   const float* lin_b, const float* comb_b0,
                                                   u16* hbf, u16* basesb, u16* wcoefb){
    __shared__ u16 lA[16 * 136];
    int tid = threadIdx.x;
    int lane = tid & 63, wv = tid >> 6;
    int n0 = blockIdx.x * 16;
    int l15 = lane & 15, lhi = lane >> 4;

    const float* xr = x + (size_t)(n0 + l15) * HIDC;
    short8v a[4];
    for (int kt = 0; kt < 4; ++kt){
        const float4* p = (const float4*)(xr + kt * 32 + lhi * 8);
        float4 f0 = p[0], f1 = p[1];
        short8v tv;
        tv[0]=(short)f2bf(f0.x); tv[1]=(short)f2bf(f0.y); tv[2]=(short)f2bf(f0.z); tv[3]=(short)f2bf(f0.w);
        tv[4]=(short)f2bf(f1.x); tv[5]=(short)f2bf(f1.y); tv[6]=(short)f2bf(f1.z); tv[7]=(short)f2bf(f1.w);
        a[kt] = tv;
    }
    for (int ct = wv; ct < 8; ct += 4){
        const short8v* bp = ((const short8v*)wpack) + ct * 256 + lane;
        f32x4 acc = {0.f, 0.f, 0.f, 0.f};
        acc = __builtin_amdgcn_mfma_f32_16x16x32_bf16(a[0], bp[0],   acc, 0, 0, 0);
        acc = __builtin_amdgcn_mfma_f32_16x16x32_bf16(a[1], bp[64],  acc, 0, 0, 0);
        acc = __builtin_amdgcn_mfma_f32_16x16x32_bf16(a[2], bp[128], acc, 0, 0, 0);
        acc = __builtin_amdgcn_mfma_f32_16x16x32_bf16(a[3], bp[192], acc, 0, 0, 0);
        int rl0 = lhi * 4, col = ct * 16 + l15;
        float bb = lin_b[col];
        for (int r = 0; r < 4; ++r){
            u16 hb = f2bf(acc[r] + bb);
            hbf[(size_t)(n0 + rl0 + r) * HIDC + col] = hb;
            lA[(rl0 + r) * 136 + col] = hb;
        }
    }
    __syncthreads();

    const u16* ar = lA + l15 * 136;
    short8v b0 = *(const short8v*)(ar + lhi * 8);
    short8v b1 = *(const short8v*)(ar + 32 + lhi * 8);
    short8v b2 = *(const short8v*)(ar + 64 + lhi * 8);
    short8v b3 = *(const short8v*)(ar + 96 + lhi * 8);
    const u16* wl = wpack + 16384;
    for (int ct = wv; ct < 10; ct += 4){
        const short8v* bp = ((const short8v*)wl) + ct * 256 + lane;
        f32x4 acc = {0.f, 0.f, 0.f, 0.f};
        acc = __builtin_amdgcn_mfma_f32_16x16x32_bf16(b0, bp[0],   acc, 0, 0, 0);
        acc = __builtin_amdgcn_mfma_f32_16x16x32_bf16(b1, bp[64],  acc, 0, 0, 0);
        acc = __builtin_amdgcn_mfma_f32_16x16x32_bf16(b2, bp[128], acc, 0, 0, 0);
        acc = __builtin_amdgcn_mfma_f32_16x16x32_bf16(b3, bp[192], acc, 0, 0, 0);
        int r0 = n0 + lhi * 4, col = ct * 16 + l15;
        if (ct < 4){
            for (int r = 0; r < 4; ++r)
                basesb[(size_t)(r0 + r) * 64 + col] = f2bf(acc[r]);
        } else {
            int c = col - 64;
            float bb = comb_b0[c];
            for (int r = 0; r < 4; ++r)
                wcoefb[(size_t)(r0 + r) * 96 + c] = f2bf(acc[r] + bb);
        }
    }
}

// ------------- fused: edge aggregation (dwordx2, 4 edges/wave-load) + combine --
__global__ __launch_bounds__(256) void k_aggcmb(const u16* __restrict__ basesb,
                                                const int* __restrict__ rowptr,
                                                const int* __restrict__ ssrc,
                                                const u16* __restrict__ wcoefb,
                                                const float* __restrict__ conv_b_l,
                                                u16* __restrict__ gbufb){
    __shared__ float sAgg[4 * 128];
    __shared__ float sInv[4];
    int tid = threadIdx.x;
    int wv = tid >> 6, lane = tid & 63;
    int slot = lane >> 4;          // edge-within-quad
    int q = lane & 15;             // channel quad: channels 4q..4q+3
    int n = blockIdx.x * 4 + wv;
    int rp0 = rowptr[n], rp1 = rowptr[n + 1];
    float s0 = 0.f, s1 = 0.f, s2 = 0.f, s3 = 0.f;
    float m0 = -INFINITY, m1 = -INFINITY, m2 = -INFINITY, m3 = -INFINITY;

    int e0 = rp0;
    // main: 8-edge chunks; each dwordx2 load serves 4 edges (16 lanes/row)
    for (; e0 + 8 <= rp1; e0 += 8){
        int idxv = ssrc[e0 + (lane & 7)];
        #pragma unroll
        for (int j = 0; j < 2; ++j){
            int i = __shfl(idxv, j * 4 + slot);
            uint2 u = *(const uint2*)(basesb + ((size_t)i << 6) + 4 * q);
            float f0 = bfl(u.x), f1 = bfh(u.x), f2 = bfl(u.y), f3 = bfh(u.y);
            s0 += f0; s1 += f1; s2 += f2; s3 += f3;
            m0 = fmaxf(m0, f0); m1 = fmaxf(m1, f1);
            m2 = fmaxf(m2, f2); m3 = fmaxf(m3, f3);
        }
    }
    // tail: up to 7 edges
    {
        int r = rp1 - e0;
        if (r > 0){
            int idxc = ssrc[min(e0 + (lane & 7), rp1 - 1)];
            #pragma unroll
            for (int j = 0; j < 2; ++j){
                int i = __shfl(idxc, j * 4 + slot);
                if (j * 4 + slot < r){
                    uint2 u = *(const uint2*)(basesb + ((size_t)i << 6) + 4 * q);
                    float f0 = bfl(u.x), f1 = bfh(u.x), f2 = bfl(u.y), f3 = bfh(u.y);
                    s0 += f0; s1 += f1; s2 += f2; s3 += f3;
                    m0 = fmaxf(m0, f0); m1 = fmaxf(m1, f1);
                    m2 = fmaxf(m2, f2); m3 = fmaxf(m3, f3);
                }
            }
        }
    }
    // butterfly-merge the 4 edge slots (lanes q, q+16, q+32, q+48)
    s0 += __shfl_xor(s0, 16); s1 += __shfl_xor(s1, 16);
    s2 += __shfl_xor(s2, 16); s3 += __shfl_xor(s3, 16);
    m0 = fmaxf(m0, __shfl_xor(m0, 16)); m1 = fmaxf(m1, __shfl_xor(m1, 16));
    m2 = fmaxf(m2, __shfl_xor(m2, 16)); m3 = fmaxf(m3, __shfl_xor(m3, 16));
    s0 += __shfl_xor(s0, 32); s1 += __shfl_xor(s1, 32);
    s2 += __shfl_xor(s2, 32); s3 += __shfl_xor(s3, 32);
    m0 = fmaxf(m0, __shfl_xor(m0, 32)); m1 = fmaxf(m1, __shfl_xor(m1, 32));
    m2 = fmaxf(m2, __shfl_xor(m2, 32)); m3 = fmaxf(m3, __shfl_xor(m3, 32));
    int degn = rp1 - rp0;
    if (degn == 0){ m0 = 0.f; m1 = 0.f; m2 = 0.f; m3 = 0.f; }
    if (slot == 0){
        float* ap = sAgg + wv * 128;
        *(float4*)(ap + 4 * q)      = make_float4(s0, s1, s2, s3);
        *(float4*)(ap + 64 + 4 * q) = make_float4(m0, m1, m2, m3);
        if (q == 0) sInv[wv] = 1.0f / fmaxf((float)degn, 1.0f);
    }
    __syncthreads();

    // phase 2: g = einsum(w, [sum; mean; max]) + conv_b  -> gbuf (bf16)
    int c = tid & 127, sub = tid >> 7;
    int f = c & 15, hh = c >> 4;
    float cb = conv_b_l[c];
    for (int i = 0; i < 2; ++i){
        int nb = i * 2 + sub;
        int n2 = blockIdx.x * 4 + nb;
        const u32* wu = (const u32*)(wcoefb + (size_t)n2 * 96 + hh * 12);
        u32 q0 = wu[0], q1 = wu[1], q2 = wu[2], q3 = wu[3], q4 = wu[4], q5 = wu[5];
        const float* ap = sAgg + nb * 128;
        float inv = sInv[nb];
        float sA = ap[f],      sB = ap[16 + f], sC = ap[32 + f], sD = ap[48 + f];
        float xA = ap[64 + f], xB = ap[80 + f], xC = ap[96 + f], xD = ap[112 + f];
        float g = cb;
        g += bfl(q0) * sA + bfh(q0) * sB + bfl(q1) * sC + bfh(q1) * sD;
        g += (bfl(q2) * sA + bfh(q2) * sB + bfl(q3) * sC + bfh(q3) * sD) * inv;
        g += bfl(q4) * xA + bfh(q4) * xB + bfl(q5) * xC + bfh(q5) * xD;
        gbufb[(size_t)n2 * HIDC + c] = f2bf(g);
    }
}

// ------------- per-graph stats from gbuf (bf16): parallel, u32 loads ----------
// grid 782 x 256: block = 128 nodes; thread = (channel-pair c2, row r of 4);
// wave reads one full 256B row per iteration (coalesced).
__global__ __launch_bounds__(256) void k_stats(const u16* __restrict__ gbufb,
                                               const int* __restrict__ batch,
                                               float* gs1, float* gs2){
    int tid = threadIdx.x;
    int c2 = tid & 63;         // u32 index: channels 2c2, 2c2+1
    int r  = tid >> 6;         // 0..3
    int n0 = blockIdx.x * 128;
    float a0 = 0.f, a1 = 0.f, b0 = 0.f, b1 = 0.f;
    int curG = -1;
    #pragma unroll 4
    for (int it = 0; it < 32; ++it){
        int n = n0 + it * 4 + r;
        if (n >= NN) break;
        u32 u = *(const u32*)(gbufb + (size_t)n * HIDC + 2 * c2);
        int bg = batch[n];
        float g0 = bfl(u), g1 = bfh(u);
        if (bg != curG){
            if (curG >= 0){
                atomicAdd(&gs1[curG * HIDC + 2 * c2],     a0);
                atomicAdd(&gs1[curG * HIDC + 2 * c2 + 1], a1);
                atomicAdd(&gs2[curG * HIDC + 2 * c2],     b0);
                atomicAdd(&gs2[curG * HIDC + 2 * c2 + 1], b1);
            }
            curG = bg; a0 = a1 = b0 = b1 = 0.f;
        }
        a0 += g0; a1 += g1; b0 += g0 * g0; b1 += g1 * g1;
    }
    if (curG >= 0){
        atomicAdd(&gs1[curG * HIDC + 2 * c2],     a0);
        atomicAdd(&gs1[curG * HIDC + 2 * c2 + 1], a1);
        atomicAdd(&gs2[curG * HIDC + 2 * c2],     b0);
        atomicAdd(&gs2[curG * HIDC + 2 * c2 + 1], b1);
    }
}

__global__ __launch_bounds__(256) void k_finalize(float* gs1, float* gs2, const int* npg,
                                                  const float* gn_ms_l, const float* gn_w_l,
                                                  float* meanms, float* winv){
    int idx = blockIdx.x * 256 + threadIdx.x;   // 8192
    int bg = idx >> 7, c = idx & 127;
    float cnt = fmaxf((float)npg[bg], 1.0f);
    float s1 = gs1[idx], s2 = gs2[idx];
    float mean = s1 / cnt, ex2 = s2 / cnt;
    float ms = gn_ms_l[c];
    float var = ex2 - mean * mean * ms * (2.0f - ms);
    float inv = rsqrtf(fmaxf(var, 0.f) + 1e-6f);
    meanms[idx] = mean * ms;
    winv[idx]   = gn_w_l[c] * inv;
    gs1[idx] = 0.f; gs2[idx] = 0.f;   // reset for next layer
}

// ------------- fused: norm+relu+residual (bf16 h) -> next-layer GEMM -----------
__global__ __launch_bounds__(256) void k_upgemm(const u16* __restrict__ gbufb,
                                                const int* __restrict__ batch,
                                                const float* meanms, const float* winv,
                                                const float* gn_b_l, u16* hbf,
                                                const u16* wp_next, const float* comb_b_next,
                                                u16* basesb, u16* wcoefb){
    __shared__ u16 lA[16 * 136];
    int tid = threadIdx.x;
    int n0 = blockIdx.x * 16;
    {
        int c = tid & 127, half = tid >> 7;
        float gb = gn_b_l[c];
        for (int i = 0; i < 8; ++i){
            int r = i * 2 + half;
            int n = n0 + r;
            int bg = batch[n];
            float g = bf1(gbufb[(size_t)n * HIDC + c]);
            float val = fmaxf((g - meanms[bg * HIDC + c]) * winv[bg * HIDC + c] + gb, 0.f);
            float hn = bf1(hbf[(size_t)n * HIDC + c]) + val;
            u16 hb = f2bf(hn);
            hbf[(size_t)n * HIDC + c] = hb;
            lA[r * 136 + c] = hb;
        }
    }
    __syncthreads();

    int lane = tid & 63, wv = tid >> 6;
    int l15 = lane & 15, lhi = lane >> 4;
    const u16* ar = lA + l15 * 136;
    short8v b0 = *(const short8v*)(ar + lhi * 8);
    short8v b1 = *(const short8v*)(ar + 32 + lhi * 8);
    short8v b2 = *(const short8v*)(ar + 64 + lhi * 8);
    short8v b3 = *(const short8v*)(ar + 96 + lhi * 8);
    for (int ct = wv; ct < 10; ct += 4){
        const short8v* bp = ((const short8v*)wp_next) + ct * 256 + lane;
        f32x4 acc = {0.f, 0.f, 0.f, 0.f};
        acc = __builtin_amdgcn_mfma_f32_16x16x32_bf16(b0, bp[0],   acc, 0, 0, 0);
        acc = __builtin_amdgcn_mfma_f32_16x16x32_bf16(b1, bp[64],  acc, 0, 0, 0);
        acc = __builtin_amdgcn_mfma_f32_16x16x32_bf16(b2, bp[128], acc, 0, 0, 0);
        acc = __builtin_amdgcn_mfma_f32_16x16x32_bf16(b3, bp[192], acc, 0, 0, 0);
        int r0 = n0 + lhi * 4, col = ct * 16 + l15;
        if (ct < 4){
            for (int r = 0; r < 4; ++r)
                basesb[(size_t)(r0 + r) * 64 + col] = f2bf(acc[r]);
        } else {
            int c = col - 64;
            float bb = comb_b_next[c];
            for (int r = 0; r < 4; ++r)
                wcoefb[(size_t)(r0 + r) * 96 + c] = f2bf(acc[r] + bb);
        }
    }
}

// ------------- last layer: norm+relu+residual -> fp32 hout + mean-pool ---------
__global__ __launch_bounds__(256) void k_uplast(const u16* __restrict__ gbufb,
                                                const int* __restrict__ batch,
                                                const float* meanms, const float* winv,
                                                const float* gn_b_l,
                                                const u16* __restrict__ hbf,
                                                float* hout, float* ysum){
    int tid = threadIdx.x;
    int c = tid & 127, half = tid >> 7;
    int n0 = blockIdx.x * 8;
    float gb = gn_b_l[c];
    float accY = 0.f; int curG = -1;
    for (int i = 0; i < 4; ++i){
        int n = n0 + i * 2 + half;
        int bg = batch[n];
        float g = bf1(gbufb[(size_t)n * HIDC + c]);
        float val = fmaxf((g - meanms[bg * HIDC + c]) * winv[bg * HIDC + c] + gb, 0.f);
        float hn = bf1(hbf[(size_t)n * HIDC + c]) + val;
        hout[(size_t)n * HIDC + c] = hn;
        if (bg != curG){
            if (curG >= 0) atomicAdd(&ysum[curG * HIDC + c], accY);
            curG = bg; accY = 0.f;
        }
        accY += hn;
    }
    if (curG >= 0) atomicAdd(&ysum[curG * HIDC + c], accY);
}

__global__ __launch_bounds__(256) void k_yscale(float* y, const int* npg){
    int idx = blockIdx.x * 256 + threadIdx.x;  // 8192
    int bg = idx >> 7;
    y[idx] /= fmaxf((float)npg[bg], 1.0f);
}

// ---------------- launch ----------------
extern "C" void kernel_launch(void* const* d_in, const int* in_sizes, int n_in,
                              void* d_out, int out_size, void* d_ws, size_t ws_size,
                              hipStream_t stream){
    const float* x       = (const float*)d_in[0];
    const int*   ei      = (const int*)d_in[1];
    const int*   batch   = (const int*)d_in[2];
    const int*   npg     = (const int*)d_in[3];
    const float* lin_w   = (const float*)d_in[4];
    const float* lin_b   = (const float*)d_in[5];
    const float* bases_w = (const float*)d_in[6];
    const float* comb_w  = (const float*)d_in[7];
    const float* comb_b  = (const float*)d_in[8];
    const float* conv_b  = (const float*)d_in[9];
    const float* gn_w    = (const float*)d_in[10];
    const float* gn_b    = (const float*)d_in[11];
    const float* gn_ms   = (const float*)d_in[12];
    (void)in_sizes; (void)n_in; (void)out_size; (void)ws_size;

    float* hout = (float*)d_out;
    float* yout = hout + (size_t)NN * HIDC;

    char* basep = (char*)d_ws;
    size_t o = 0;
    auto alloc = [&](size_t bytes) -> char* {
        char* p = basep + o;
        o = (o + bytes + 255) & ~(size_t)255;
        return p;
    };
    u16*   wpack  = (u16*)  alloc((size_t)98304 * 2);
    u16*   hbf    = (u16*)  alloc((size_t)NN * HIDC * 2);
    u16*   basesb = (u16*)  alloc((size_t)NN * 64 * 2);
    u16*   wcoefb = (u16*)  alloc((size_t)NN * 96 * 2);
    u16*   gbufb  = (u16*)  alloc((size_t)NN * HIDC * 2);
    int*   rowptr = (int*)  alloc((size_t)(NN + 1) * 4);
    int*   ssrc   = (int*)  alloc((size_t)EE * 4);
    u32*   esort  = (u32*)  alloc((size_t)EE * 4);
    int*   bcnt   = (int*)  alloc((size_t)NBK * 4);
    int*   boff   = (int*)  alloc((size_t)(NBK + 1) * 4);
    int*   gcur   = (int*)  alloc((size_t)NBK * 4);
    float* gs1    = (float*)alloc(8192 * 4);
    float* gs2    = (float*)alloc(8192 * 4);
    float* meanms = (float*)alloc(8192 * 4);
    float* winv   = (float*)alloc(8192 * 4);

    hipMemsetAsync(bcnt, 0, (size_t)NBK * 4, stream);
    hipMemsetAsync(gs1,  0, (size_t)8192 * 4, stream);
    hipMemsetAsync(gs2,  0, (size_t)8192 * 4, stream);
    hipMemsetAsync(yout, 0, (size_t)8192 * 4, stream);

    k_pack <<<384, 256, 0, stream>>>(lin_w, bases_w, comb_w, wpack);
    k_bhist<<<800, 256, 0, stream>>>(ei + EE, bcnt);
    k_bscan<<<1,   512, 0, stream>>>(bcnt, boff, gcur);
    k_binA <<<800, 256, 0, stream>>>(ei, ei + EE, gcur, esort);
    k_binB <<<NBK, 512, 0, stream>>>(esort, boff, rowptr, ssrc);

    k_lin_gemm0<<<6250, 256, 0, stream>>>(x, wpack, lin_b, comb_b, hbf, basesb, wcoefb);

    for (int l = 0; l < LL; ++l){
        k_aggcmb  <<<25000, 256, 0, stream>>>(basesb, rowptr, ssrc, wcoefb,
                                              conv_b + l * HIDC, gbufb);
        k_stats   <<<782,   256, 0, stream>>>(gbufb, batch, gs1, gs2);
        k_finalize<<<32,    256, 0, stream>>>(gs1, gs2, npg, gn_ms + l * HIDC,
                                              gn_w + l * HIDC, meanms, winv);
        if (l < 3){
            k_upgemm<<<6250, 256, 0, stream>>>(gbufb, batch, meanms, winv,
                                               gn_b + l * HIDC, hbf,
                                               wpack + 16384 + (l + 1) * 20480,
                                               comb_b + (l + 1) * 96, basesb, wcoefb);
        } else {
            k_uplast<<<12500, 256, 0, stream>>>(gbufb, batch, meanms, winv,
                                                gn_b + l * HIDC, hbf, hout, yout);
        }
    }
    k_yscale<<<32, 256, 0, stream>>>(yout, npg);
}